// Round 1
// 733.239 us; speedup vs baseline: 1.0176x; 1.0176x over previous
//
#include <hip/hip_runtime.h>

#define NNODES 100000
#define NEDGES 1600000
#define DD 128
#define K1 256
#define BM 32

// ---------------- workspace layout (ints) ----------------
// cnt[100000] | offs[100001] | esrc[1600000]
// The cnt region is dead after fill_kernel; wprep_kernel reuses it for the
// split-bf16 transposed weight tables (256KB needed, 400KB available).
#define WS_CNT 0
#define WS_OFFS 100352
#define WS_ESRC 201216

// ushort offsets inside the cnt region
#define WT1HI 0        // [128][256]
#define WT1LO 32768
#define WT2HI 65536    // [128][128]
#define WT2LO 81920
#define WT3HI 98304
#define WT3LO 114688

typedef __attribute__((ext_vector_type(8))) short short8;  // 8 bf16 (4 VGPR)
typedef __attribute__((ext_vector_type(4))) float f32x4;

// x ~= hi + lo, both bf16 (RNE). hi*whi + hi*wlo + lo*whi gives ~2^-16 rel err.
__device__ __forceinline__ void bf16_split(float x, ushort& hi, ushort& lo) {
  unsigned u = __float_as_uint(x);
  ushort h = (ushort)((u + 0x7FFFu + ((u >> 16) & 1u)) >> 16);
  float r = x - __uint_as_float(((unsigned)h) << 16);  // exact in fp32
  unsigned v = __float_as_uint(r);
  ushort l = (ushort)((v + 0x7FFFu + ((v >> 16) & 1u)) >> 16);
  hi = h;
  lo = l;
}

// ---------------- CSR build (unchanged) ----------------
__global__ __launch_bounds__(256) void hist_kernel(const int* __restrict__ dst,
                                                   int* __restrict__ cnt) {
  int e = blockIdx.x * 256 + threadIdx.x;
  if (e < NEDGES) atomicAdd(&cnt[dst[e]], 1);
}

__global__ __launch_bounds__(1024) void scan_kernel(int* __restrict__ cnt,
                                                    int* __restrict__ offs) {
  __shared__ int sums[1024];
  const int t = threadIdx.x;
  const int beg = t * 98;
  const int end = min(beg + 98, NNODES);
  int local = 0;
  for (int i = beg; i < end; ++i) local += cnt[i];
  sums[t] = local;
  __syncthreads();
  for (int off = 1; off < 1024; off <<= 1) {
    int v = (t >= off) ? sums[t - off] : 0;
    __syncthreads();
    sums[t] += v;
    __syncthreads();
  }
  int run = sums[t] - local;
  for (int i = beg; i < end; ++i) {
    int d = cnt[i];
    offs[i] = run;
    cnt[i] = run;
    run += d;
  }
  if (t == 1023) offs[NNODES] = sums[1023];
}

__global__ __launch_bounds__(256) void fill_kernel(const int* __restrict__ src,
                                                   const int* __restrict__ dst,
                                                   int* __restrict__ cursor,
                                                   int* __restrict__ esrc) {
  int e = blockIdx.x * 256 + threadIdx.x;
  if (e >= NEDGES) return;
  int pos = atomicAdd(&cursor[dst[e]], 1);
  esrc[pos] = src[e];
}

// ---------------- gather-aggregate (unchanged) ----------------
__global__ __launch_bounds__(256) void agg_kernel(const float* __restrict__ nf,
                                                  const int* __restrict__ offs,
                                                  const int* __restrict__ esrc,
                                                  float* __restrict__ agg) {
  const int t = threadIdx.x;
  const int node = blockIdx.x * 8 + (t >> 5);
  const int c4 = (t & 31) << 2;
  const int beg = offs[node];
  const int end = offs[node + 1];
  float4 a0 = make_float4(0.f, 0.f, 0.f, 0.f);
  float4 a1 = make_float4(0.f, 0.f, 0.f, 0.f);
  int i = beg;
  for (; i + 1 < end; i += 2) {
    int s0 = esrc[i];
    int s1 = esrc[i + 1];
    float4 v0 = *(const float4*)&nf[s0 * DD + c4];
    float4 v1 = *(const float4*)&nf[s1 * DD + c4];
    a0.x += v0.x; a0.y += v0.y; a0.z += v0.z; a0.w += v0.w;
    a1.x += v1.x; a1.y += v1.y; a1.z += v1.z; a1.w += v1.w;
  }
  if (i < end) {
    int s0 = esrc[i];
    float4 v0 = *(const float4*)&nf[s0 * DD + c4];
    a0.x += v0.x; a0.y += v0.y; a0.z += v0.z; a0.w += v0.w;
  }
  a0.x += a1.x; a0.y += a1.y; a0.z += a1.z; a0.w += a1.w;
  *(float4*)&agg[node * DD + c4] = a0;
}

// ---------------- weight prep: fp32 -> split-bf16, transposed [N][K] ----------------
__global__ __launch_bounds__(256) void wprep_kernel(const float* __restrict__ W1,
                                                    const float* __restrict__ W2,
                                                    const float* __restrict__ W3,
                                                    ushort* __restrict__ wt) {
  int tid = blockIdx.x * 256 + threadIdx.x;  // 65536 total
  ushort hi, lo;
  if (tid < 32768) {
    int n = tid >> 8, k = tid & 255;          // out = [n][k], in = W1[k][n]
    bf16_split(W1[k * DD + n], hi, lo);
    wt[WT1HI + tid] = hi;
    wt[WT1LO + tid] = lo;
  } else {
    int t2 = tid - 32768;
    int which = t2 >> 14;                     // 0 -> W2, 1 -> W3
    int idx = t2 & 16383;
    int n = idx >> 7, k = idx & 127;
    const float* W = which ? W3 : W2;
    bf16_split(W[k * DD + n], hi, lo);
    wt[(which ? WT3HI : WT2HI) + idx] = hi;
    wt[(which ? WT3LO : WT2LO) + idx] = lo;
  }
}

// ---------------- MFMA MLP ----------------
// Per block: 32 rows, 4 waves. Wave w: row-tile rt=w&1 (16 rows),
// col half ch=w>>1 (4x 16-col tiles). A from swizzled LDS, B (weights)
// streamed 16B/lane from the L2-resident transposed tables.
// A-frag (16x16x32): lane l holds A[row = l&15][k = (l>>4)*8 + j]
// B-frag:            lane l holds B[k = (l>>4)*8 + j][col = l&15]
// C/D:               lane l reg i -> row = (l>>4)*4 + i, col = l&15   [m89/m91]
template <int K, int RS>  // K = reduce dim, RS = LDS row stride (bytes)
__device__ __forceinline__ void layer_mfma(const ushort* Ahi, const ushort* Alo,
                                           const ushort* __restrict__ WhiT,
                                           const ushort* __restrict__ WloT,
                                           int rt, int ch, int l15, int lhi,
                                           f32x4 acc[4]) {
  const int row = rt * 16 + l15;
  const char* ahp = (const char*)Ahi;
  const char* alp = (const char*)Alo;
  const int abase = row * RS + lhi * 16;
  const int axor = (row & 7) << 4;  // G4 XOR swizzle (matches staging writes)
  int wbase[4];
#pragma unroll
  for (int ct = 0; ct < 4; ++ct)
    wbase[ct] = (ch * 64 + ct * 16 + l15) * K + lhi * 8;
#pragma unroll 2
  for (int kk = 0; kk < K / 32; ++kk) {
    int ab = (abase + kk * 64) ^ axor;
    short8 ahi = *(const short8*)(ahp + ab);
    short8 alo = *(const short8*)(alp + ab);
#pragma unroll
    for (int ct = 0; ct < 4; ++ct) {
      short8 bhi = *(const short8*)&WhiT[wbase[ct] + kk * 32];
      short8 blo = *(const short8*)&WloT[wbase[ct] + kk * 32];
      acc[ct] = __builtin_amdgcn_mfma_f32_16x16x32_bf16(ahi, bhi, acc[ct], 0, 0, 0);
      acc[ct] = __builtin_amdgcn_mfma_f32_16x16x32_bf16(ahi, blo, acc[ct], 0, 0, 0);
      acc[ct] = __builtin_amdgcn_mfma_f32_16x16x32_bf16(alo, bhi, acc[ct], 0, 0, 0);
    }
  }
}

// bias + ReLU + split-bf16 + swizzled LDS store ([32][128], 256B stride)
__device__ __forceinline__ void store_h(ushort* Hh, ushort* Hl,
                                        const float* __restrict__ b,
                                        int rt, int ch, int l15, int lhi,
                                        f32x4 acc[4]) {
#pragma unroll
  for (int ct = 0; ct < 4; ++ct) {
    int col = ch * 64 + ct * 16 + l15;
    float bias = b[col];
#pragma unroll
    for (int i = 0; i < 4; ++i) {
      int row = rt * 16 + lhi * 4 + i;
      float v = fmaxf(acc[ct][i] + bias, 0.f);
      ushort h, l;
      bf16_split(v, h, l);
      int byte = (row * 256 + col * 2) ^ ((row & 7) << 4);
      *(ushort*)((char*)Hh + byte) = h;
      *(ushort*)((char*)Hl + byte) = l;
    }
  }
}

__global__ __launch_bounds__(256, 3) void mlp_kernel(const float* __restrict__ agg,
                                                     const float* __restrict__ nf,
                                                     const ushort* __restrict__ wt,
                                                     const float* __restrict__ b1,
                                                     const float* __restrict__ b2,
                                                     const float* __restrict__ b3,
                                                     float* __restrict__ out) {
  // Xhi[32][256] | Xlo[32][256] | Hhi[32][128] | Hlo[32][128]  = 48KB
  // layer-2 output (H2) reuses the X region (dead after layer 1 + barrier).
  __shared__ ushort smem[24576];
  ushort* Xhi = smem;
  ushort* Xlo = smem + 8192;
  ushort* Hhi = smem + 16384;
  ushort* Hlo = smem + 20480;
  ushort* H2hi = smem;
  ushort* H2lo = smem + 8192;

  const int t = threadIdx.x;
  const int base = blockIdx.x * BM;
  const int lane = t & 63;
  const int w = t >> 6;
  const int rt = w & 1;
  const int ch = w >> 1;
  const int l15 = lane & 15;
  const int lhi = lane >> 4;

  // ---- stage X = [agg | nf] rows, split to bf16 hi/lo, XOR-swizzled ----
#pragma unroll
  for (int i = 0; i < 8; ++i) {
    int idx = t + i * 256;
    int n = idx >> 6;
    int c4 = (idx & 63) << 2;  // col in [0,256), multiple of 4
    float4 v;
    if (c4 < DD)
      v = *(const float4*)&agg[(base + n) * DD + c4];
    else
      v = *(const float4*)&nf[(base + n) * DD + (c4 - DD)];
    ushort h0, h1, h2, h3, l0, l1, l2, l3;
    bf16_split(v.x, h0, l0);
    bf16_split(v.y, h1, l1);
    bf16_split(v.z, h2, l2);
    bf16_split(v.w, h3, l3);
    int byte = (n * 512 + c4 * 2) ^ ((n & 7) << 4);
    *(ushort4*)((char*)Xhi + byte) = make_ushort4(h0, h1, h2, h3);
    *(ushort4*)((char*)Xlo + byte) = make_ushort4(l0, l1, l2, l3);
  }
  __syncthreads();

  const f32x4 z = {0.f, 0.f, 0.f, 0.f};
  f32x4 acc[4];

  // ---- layer 1: [32][256] x [256][128] ----
#pragma unroll
  for (int ct = 0; ct < 4; ++ct) acc[ct] = z;
  layer_mfma<256, 512>(Xhi, Xlo, wt + WT1HI, wt + WT1LO, rt, ch, l15, lhi, acc);
  store_h(Hhi, Hlo, b1, rt, ch, l15, lhi, acc);
  __syncthreads();

  // ---- layer 2: [32][128] x [128][128] ----
#pragma unroll
  for (int ct = 0; ct < 4; ++ct) acc[ct] = z;
  layer_mfma<128, 256>(Hhi, Hlo, wt + WT2HI, wt + WT2LO, rt, ch, l15, lhi, acc);
  store_h(H2hi, H2lo, b2, rt, ch, l15, lhi, acc);
  __syncthreads();

  // ---- layer 3: [32][128] x [128][128], fp32 out ----
#pragma unroll
  for (int ct = 0; ct < 4; ++ct) acc[ct] = z;
  layer_mfma<128, 256>(H2hi, H2lo, wt + WT3HI, wt + WT3LO, rt, ch, l15, lhi, acc);
#pragma unroll
  for (int ct = 0; ct < 4; ++ct) {
    int col = ch * 64 + ct * 16 + l15;
    float bias = b3[col];
#pragma unroll
    for (int i = 0; i < 4; ++i) {
      int row = rt * 16 + lhi * 4 + i;
      out[(base + row) * DD + col] = acc[ct][i] + bias;
    }
  }
}

extern "C" void kernel_launch(void* const* d_in, const int* in_sizes, int n_in,
                              void* d_out, int out_size, void* d_ws, size_t ws_size,
                              hipStream_t stream) {
  const float* nf = (const float*)d_in[0];
  const int* src = (const int*)d_in[1];
  const int* dst = (const int*)d_in[2];
  const float* W1 = (const float*)d_in[3];
  const float* b1 = (const float*)d_in[4];
  const float* W2 = (const float*)d_in[5];
  const float* b2 = (const float*)d_in[6];
  const float* W3 = (const float*)d_in[7];
  const float* b3 = (const float*)d_in[8];
  float* out = (float*)d_out;

  int* wsi = (int*)d_ws;
  int* cnt = wsi + WS_CNT;    // 100000 ints; doubles as fill cursor, then weight tables
  int* offs = wsi + WS_OFFS;  // 100001
  int* esrc = wsi + WS_ESRC;  // 1600000
  ushort* wt = (ushort*)cnt;  // 131072 ushorts (256KB) < 400KB — safe after fill

  // agg aliases d_out: agg_kernel writes each row once; mlp_kernel stages its
  // own 32 rows into LDS before overwriting them.
  float* agg = out;

  hipMemsetAsync(cnt, 0, NNODES * sizeof(int), stream);
  hist_kernel<<<(NEDGES + 255) / 256, 256, 0, stream>>>(dst, cnt);
  scan_kernel<<<1, 1024, 0, stream>>>(cnt, offs);
  fill_kernel<<<(NEDGES + 255) / 256, 256, 0, stream>>>(src, dst, cnt, esrc);
  // cnt region is dead from here on — convert weights into it
  wprep_kernel<<<256, 256, 0, stream>>>(W1, W2, W3, wt);
  agg_kernel<<<NNODES / 8, 256, 0, stream>>>(nf, offs, esrc, agg);
  mlp_kernel<<<NNODES / BM, 256, 0, stream>>>(agg, nf, wt, b1, b2, b3, out);
}

// Round 2
// 521.548 us; speedup vs baseline: 1.4306x; 1.4059x over previous
//
#include <hip/hip_runtime.h>

#define NNODES 100000
#define NEDGES 1600000
#define DD 128
#define K1 256
#define BM 32
#define NBLK_SCAN 98  // ceil(NNODES / 1024)

// ---------------- workspace layout (ints) ----------------
// cnt[100000] | bsums[98 in slack] | offs[100001] | esrc[1600000]
// The cnt region is dead after fill_kernel; wprep_kernel reuses it for the
// split-bf16 transposed weight tables (256KB needed, 400KB available).
#define WS_CNT 0
#define WS_BSUMS 100000  // 98 ints in the [100000,100352) slack
#define WS_OFFS 100352
#define WS_ESRC 201216

// ushort offsets inside the cnt region
#define WT1HI 0        // [128][256]
#define WT1LO 32768
#define WT2HI 65536    // [128][128]
#define WT2LO 81920
#define WT3HI 98304
#define WT3LO 114688

typedef __attribute__((ext_vector_type(8))) short short8;  // 8 bf16 (4 VGPR)
typedef __attribute__((ext_vector_type(4))) float f32x4;

// x ~= hi + lo, both bf16 (RNE). hi*whi + hi*wlo + lo*whi gives ~2^-16 rel err.
__device__ __forceinline__ void bf16_split(float x, ushort& hi, ushort& lo) {
  unsigned u = __float_as_uint(x);
  ushort h = (ushort)((u + 0x7FFFu + ((u >> 16) & 1u)) >> 16);
  float r = x - __uint_as_float(((unsigned)h) << 16);  // exact in fp32
  unsigned v = __float_as_uint(r);
  ushort l = (ushort)((v + 0x7FFFu + ((v >> 16) & 1u)) >> 16);
  hi = h;
  lo = l;
}

// ---------------- CSR build ----------------
__global__ __launch_bounds__(256) void hist_kernel(const int* __restrict__ dst,
                                                   int* __restrict__ cnt) {
  int e = blockIdx.x * 256 + threadIdx.x;
  if (e < NEDGES) atomicAdd(&cnt[dst[e]], 1);
}

// Phase 1: per-block sums of cnt (98 blocks x 1024)
__global__ __launch_bounds__(1024) void bsum_kernel(const int* __restrict__ cnt,
                                                    int* __restrict__ bsums) {
  __shared__ int red[16];
  const int t = threadIdx.x;
  const int i = blockIdx.x * 1024 + t;
  int v = (i < NNODES) ? cnt[i] : 0;
#pragma unroll
  for (int off = 32; off > 0; off >>= 1) v += __shfl_down(v, off, 64);
  if ((t & 63) == 0) red[t >> 6] = v;
  __syncthreads();
  if (t < 16) {
    int s = red[t];
#pragma unroll
    for (int off = 8; off > 0; off >>= 1) s += __shfl_down(s, off, 16);
    if (t == 0) bsums[blockIdx.x] = s;
  }
}

// Phase 2: exclusive scan of the 98 block sums (single tiny block);
// also writes offs[NNODES] = total edge count.
__global__ __launch_bounds__(128) void bscan_kernel(int* __restrict__ bsums,
                                                    int* __restrict__ offs) {
  __shared__ int s[128];
  const int t = threadIdx.x;
  int v = (t < NBLK_SCAN) ? bsums[t] : 0;
  s[t] = v;
  __syncthreads();
  for (int off = 1; off < 128; off <<= 1) {
    int u = (t >= off) ? s[t - off] : 0;
    __syncthreads();
    s[t] += u;
    __syncthreads();
  }
  if (t < NBLK_SCAN) bsums[t] = s[t] - v;  // exclusive block prefix
  if (t == NBLK_SCAN - 1) offs[NNODES] = s[t];
}

// Phase 3: intra-block exclusive scan + block offset -> offs & cursor init.
__global__ __launch_bounds__(1024) void offs_kernel(int* __restrict__ cnt,
                                                    const int* __restrict__ bsums,
                                                    int* __restrict__ offs) {
  __shared__ int s[1024];
  const int t = threadIdx.x;
  const int i = blockIdx.x * 1024 + t;
  int v = (i < NNODES) ? cnt[i] : 0;
  s[t] = v;
  __syncthreads();
  for (int off = 1; off < 1024; off <<= 1) {
    int u = (t >= off) ? s[t - off] : 0;
    __syncthreads();
    s[t] += u;
    __syncthreads();
  }
  int excl = s[t] - v + bsums[blockIdx.x];
  if (i < NNODES) {
    offs[i] = excl;
    cnt[i] = excl;  // cursor init for fill_kernel
  }
}

__global__ __launch_bounds__(256) void fill_kernel(const int* __restrict__ src,
                                                   const int* __restrict__ dst,
                                                   int* __restrict__ cursor,
                                                   int* __restrict__ esrc) {
  int e = blockIdx.x * 256 + threadIdx.x;
  if (e >= NEDGES) return;
  int pos = atomicAdd(&cursor[dst[e]], 1);
  esrc[pos] = src[e];
}

// ---------------- gather-aggregate (unchanged) ----------------
__global__ __launch_bounds__(256) void agg_kernel(const float* __restrict__ nf,
                                                  const int* __restrict__ offs,
                                                  const int* __restrict__ esrc,
                                                  float* __restrict__ agg) {
  const int t = threadIdx.x;
  const int node = blockIdx.x * 8 + (t >> 5);
  const int c4 = (t & 31) << 2;
  const int beg = offs[node];
  const int end = offs[node + 1];
  float4 a0 = make_float4(0.f, 0.f, 0.f, 0.f);
  float4 a1 = make_float4(0.f, 0.f, 0.f, 0.f);
  int i = beg;
  for (; i + 1 < end; i += 2) {
    int s0 = esrc[i];
    int s1 = esrc[i + 1];
    float4 v0 = *(const float4*)&nf[s0 * DD + c4];
    float4 v1 = *(const float4*)&nf[s1 * DD + c4];
    a0.x += v0.x; a0.y += v0.y; a0.z += v0.z; a0.w += v0.w;
    a1.x += v1.x; a1.y += v1.y; a1.z += v1.z; a1.w += v1.w;
  }
  if (i < end) {
    int s0 = esrc[i];
    float4 v0 = *(const float4*)&nf[s0 * DD + c4];
    a0.x += v0.x; a0.y += v0.y; a0.z += v0.z; a0.w += v0.w;
  }
  a0.x += a1.x; a0.y += a1.y; a0.z += a1.z; a0.w += a1.w;
  *(float4*)&agg[node * DD + c4] = a0;
}

// ---------------- weight prep: fp32 -> split-bf16, transposed [N][K] ----------------
__global__ __launch_bounds__(256) void wprep_kernel(const float* __restrict__ W1,
                                                    const float* __restrict__ W2,
                                                    const float* __restrict__ W3,
                                                    ushort* __restrict__ wt) {
  int tid = blockIdx.x * 256 + threadIdx.x;  // 65536 total
  ushort hi, lo;
  if (tid < 32768) {
    int n = tid >> 8, k = tid & 255;          // out = [n][k], in = W1[k][n]
    bf16_split(W1[k * DD + n], hi, lo);
    wt[WT1HI + tid] = hi;
    wt[WT1LO + tid] = lo;
  } else {
    int t2 = tid - 32768;
    int which = t2 >> 14;                     // 0 -> W2, 1 -> W3
    int idx = t2 & 16383;
    int n = idx >> 7, k = idx & 127;
    const float* W = which ? W3 : W2;
    bf16_split(W[k * DD + n], hi, lo);
    wt[(which ? WT3HI : WT2HI) + idx] = hi;
    wt[(which ? WT3LO : WT2LO) + idx] = lo;
  }
}

// ---------------- MFMA MLP ----------------
// Per block: 32 rows, 4 waves. Wave w: row-tile rt=w&1 (16 rows),
// col half ch=w>>1 (4x 16-col tiles). A from swizzled LDS, B (weights)
// streamed 16B/lane from the L2-resident transposed tables.
// A-frag (16x16x32): lane l holds A[row = l&15][k = (l>>4)*8 + j]
// B-frag:            lane l holds B[k = (l>>4)*8 + j][col = l&15]
// C/D:               lane l reg i -> row = (l>>4)*4 + i, col = l&15   [m89/m91]
template <int K, int RS>  // K = reduce dim, RS = LDS row stride (bytes)
__device__ __forceinline__ void layer_mfma(const ushort* Ahi, const ushort* Alo,
                                           const ushort* __restrict__ WhiT,
                                           const ushort* __restrict__ WloT,
                                           int rt, int ch, int l15, int lhi,
                                           f32x4 acc[4]) {
  const int row = rt * 16 + l15;
  const char* ahp = (const char*)Ahi;
  const char* alp = (const char*)Alo;
  const int abase = row * RS + lhi * 16;
  const int axor = (row & 7) << 4;  // G4 XOR swizzle (matches staging writes)
  int wbase[4];
#pragma unroll
  for (int ct = 0; ct < 4; ++ct)
    wbase[ct] = (ch * 64 + ct * 16 + l15) * K + lhi * 8;
#pragma unroll 2
  for (int kk = 0; kk < K / 32; ++kk) {
    int ab = (abase + kk * 64) ^ axor;
    short8 ahi = *(const short8*)(ahp + ab);
    short8 alo = *(const short8*)(alp + ab);
#pragma unroll
    for (int ct = 0; ct < 4; ++ct) {
      short8 bhi = *(const short8*)&WhiT[wbase[ct] + kk * 32];
      short8 blo = *(const short8*)&WloT[wbase[ct] + kk * 32];
      acc[ct] = __builtin_amdgcn_mfma_f32_16x16x32_bf16(ahi, bhi, acc[ct], 0, 0, 0);
      acc[ct] = __builtin_amdgcn_mfma_f32_16x16x32_bf16(ahi, blo, acc[ct], 0, 0, 0);
      acc[ct] = __builtin_amdgcn_mfma_f32_16x16x32_bf16(alo, bhi, acc[ct], 0, 0, 0);
    }
  }
}

// bias + ReLU + split-bf16 + swizzled LDS store ([32][128], 256B stride)
__device__ __forceinline__ void store_h(ushort* Hh, ushort* Hl,
                                        const float* __restrict__ b,
                                        int rt, int ch, int l15, int lhi,
                                        f32x4 acc[4]) {
#pragma unroll
  for (int ct = 0; ct < 4; ++ct) {
    int col = ch * 64 + ct * 16 + l15;
    float bias = b[col];
#pragma unroll
    for (int i = 0; i < 4; ++i) {
      int row = rt * 16 + lhi * 4 + i;
      float v = fmaxf(acc[ct][i] + bias, 0.f);
      ushort h, l;
      bf16_split(v, h, l);
      int byte = (row * 256 + col * 2) ^ ((row & 7) << 4);
      *(ushort*)((char*)Hh + byte) = h;
      *(ushort*)((char*)Hl + byte) = l;
    }
  }
}

__global__ __launch_bounds__(256, 3) void mlp_kernel(const float* __restrict__ agg,
                                                     const float* __restrict__ nf,
                                                     const ushort* __restrict__ wt,
                                                     const float* __restrict__ b1,
                                                     const float* __restrict__ b2,
                                                     const float* __restrict__ b3,
                                                     float* __restrict__ out) {
  // Xhi[32][256] | Xlo[32][256] | Hhi[32][128] | Hlo[32][128]  = 48KB
  // layer-2 output (H2) reuses the X region (dead after layer 1 + barrier).
  __shared__ ushort smem[24576];
  ushort* Xhi = smem;
  ushort* Xlo = smem + 8192;
  ushort* Hhi = smem + 16384;
  ushort* Hlo = smem + 20480;
  ushort* H2hi = smem;
  ushort* H2lo = smem + 8192;

  const int t = threadIdx.x;
  const int base = blockIdx.x * BM;
  const int lane = t & 63;
  const int w = t >> 6;
  const int rt = w & 1;
  const int ch = w >> 1;
  const int l15 = lane & 15;
  const int lhi = lane >> 4;

  // ---- stage X = [agg | nf] rows, split to bf16 hi/lo, XOR-swizzled ----
#pragma unroll
  for (int i = 0; i < 8; ++i) {
    int idx = t + i * 256;
    int n = idx >> 6;
    int c4 = (idx & 63) << 2;  // col in [0,256), multiple of 4
    float4 v;
    if (c4 < DD)
      v = *(const float4*)&agg[(base + n) * DD + c4];
    else
      v = *(const float4*)&nf[(base + n) * DD + (c4 - DD)];
    ushort h0, h1, h2, h3, l0, l1, l2, l3;
    bf16_split(v.x, h0, l0);
    bf16_split(v.y, h1, l1);
    bf16_split(v.z, h2, l2);
    bf16_split(v.w, h3, l3);
    int byte = (n * 512 + c4 * 2) ^ ((n & 7) << 4);
    *(ushort4*)((char*)Xhi + byte) = make_ushort4(h0, h1, h2, h3);
    *(ushort4*)((char*)Xlo + byte) = make_ushort4(l0, l1, l2, l3);
  }
  __syncthreads();

  const f32x4 z = {0.f, 0.f, 0.f, 0.f};
  f32x4 acc[4];

  // ---- layer 1: [32][256] x [256][128] ----
#pragma unroll
  for (int ct = 0; ct < 4; ++ct) acc[ct] = z;
  layer_mfma<256, 512>(Xhi, Xlo, wt + WT1HI, wt + WT1LO, rt, ch, l15, lhi, acc);
  store_h(Hhi, Hlo, b1, rt, ch, l15, lhi, acc);
  __syncthreads();

  // ---- layer 2: [32][128] x [128][128] ----
#pragma unroll
  for (int ct = 0; ct < 4; ++ct) acc[ct] = z;
  layer_mfma<128, 256>(Hhi, Hlo, wt + WT2HI, wt + WT2LO, rt, ch, l15, lhi, acc);
  store_h(H2hi, H2lo, b2, rt, ch, l15, lhi, acc);
  __syncthreads();

  // ---- layer 3: [32][128] x [128][128], fp32 out ----
#pragma unroll
  for (int ct = 0; ct < 4; ++ct) acc[ct] = z;
  layer_mfma<128, 256>(H2hi, H2lo, wt + WT3HI, wt + WT3LO, rt, ch, l15, lhi, acc);
#pragma unroll
  for (int ct = 0; ct < 4; ++ct) {
    int col = ch * 64 + ct * 16 + l15;
    float bias = b3[col];
#pragma unroll
    for (int i = 0; i < 4; ++i) {
      int row = rt * 16 + lhi * 4 + i;
      out[(base + row) * DD + col] = acc[ct][i] + bias;
    }
  }
}

extern "C" void kernel_launch(void* const* d_in, const int* in_sizes, int n_in,
                              void* d_out, int out_size, void* d_ws, size_t ws_size,
                              hipStream_t stream) {
  const float* nf = (const float*)d_in[0];
  const int* src = (const int*)d_in[1];
  const int* dst = (const int*)d_in[2];
  const float* W1 = (const float*)d_in[3];
  const float* b1 = (const float*)d_in[4];
  const float* W2 = (const float*)d_in[5];
  const float* b2 = (const float*)d_in[6];
  const float* W3 = (const float*)d_in[7];
  const float* b3 = (const float*)d_in[8];
  float* out = (float*)d_out;

  int* wsi = (int*)d_ws;
  int* cnt = wsi + WS_CNT;      // 100000 ints; cursor, then weight tables
  int* bsums = wsi + WS_BSUMS;  // 98 ints (slack)
  int* offs = wsi + WS_OFFS;    // 100001
  int* esrc = wsi + WS_ESRC;    // 1600000
  ushort* wt = (ushort*)cnt;    // 131072 ushorts (256KB) — safe after fill

  // agg aliases d_out: agg_kernel writes each row once; mlp_kernel stages its
  // own 32 rows into LDS before overwriting them.
  float* agg = out;

  hipMemsetAsync(cnt, 0, NNODES * sizeof(int), stream);
  hist_kernel<<<(NEDGES + 255) / 256, 256, 0, stream>>>(dst, cnt);
  bsum_kernel<<<NBLK_SCAN, 1024, 0, stream>>>(cnt, bsums);
  bscan_kernel<<<1, 128, 0, stream>>>(bsums, offs);
  offs_kernel<<<NBLK_SCAN, 1024, 0, stream>>>(cnt, bsums, offs);
  fill_kernel<<<(NEDGES + 255) / 256, 256, 0, stream>>>(src, dst, cnt, esrc);
  // cnt region is dead from here on — convert weights into it
  wprep_kernel<<<256, 256, 0, stream>>>(W1, W2, W3, wt);
  agg_kernel<<<NNODES / 8, 256, 0, stream>>>(nf, offs, esrc, agg);
  mlp_kernel<<<NNODES / BM, 256, 0, stream>>>(agg, nf, wt, b1, b2, b3, out);
}

// Round 3
// 398.373 us; speedup vs baseline: 1.8729x; 1.3092x over previous
//
#include <hip/hip_runtime.h>

#define NNODES 100000
#define NEDGES 1600000
#define DD 128
#define BM 64
#define NBLK_SCAN 98                       // ceil(NNODES / 1024)
#define NBLK_MLP ((NNODES + BM - 1) / BM)  // 1563

// ---------------- workspace layout (ints) ----------------
// cnt[100000] | bsums[98 in slack] | offs[100001] | esrc[1600000]
// cnt region is dead after fill_kernel; wprep reuses it for tile-packed
// split-bf16 weight tables (256KB needed, 400KB available).
#define WS_CNT 0
#define WS_BSUMS 100000
#define WS_OFFS 100352
#define WS_ESRC 201216

// ushort offsets inside the cnt region. Layout is TILE-PACKED:
// tile = c16*(K/32) + kk, 1KB per tile, lane-order 16B fragments:
//   wt[tileBase + lane*8 + j] = W[k = kk*32 + (lane>>4)*8 + j][col = c16*16 + (lane&15)]
#define WT1HI 0        // K=256: 8 c16 x 8 kk tiles = 32768 ushorts
#define WT1LO 32768
#define WT2HI 65536    // K=128: 8 x 4 tiles = 16384
#define WT2LO 81920
#define WT3HI 98304
#define WT3LO 114688

typedef __attribute__((ext_vector_type(8))) short short8;  // 8 bf16
typedef __attribute__((ext_vector_type(4))) float f32x4;

// x ~= hi + lo, both bf16 (RNE). hi*whi + hi*wlo + lo*whi gives ~2^-16 rel err.
__device__ __forceinline__ void bf16_split(float x, ushort& hi, ushort& lo) {
  unsigned u = __float_as_uint(x);
  ushort h = (ushort)((u + 0x7FFFu + ((u >> 16) & 1u)) >> 16);
  float r = x - __uint_as_float(((unsigned)h) << 16);  // exact in fp32
  unsigned v = __float_as_uint(r);
  ushort l = (ushort)((v + 0x7FFFu + ((v >> 16) & 1u)) >> 16);
  hi = h;
  lo = l;
}

__device__ __forceinline__ void split8(const float4 v0, const float4 v1,
                                       short8& hi, short8& lo) {
  float x[8] = {v0.x, v0.y, v0.z, v0.w, v1.x, v1.y, v1.z, v1.w};
#pragma unroll
  for (int j = 0; j < 8; ++j) {
    ushort h, l;
    bf16_split(x[j], h, l);
    hi[j] = (short)h;
    lo[j] = (short)l;
  }
}

// ---------------- CSR build ----------------
__global__ __launch_bounds__(256) void hist_kernel(const int* __restrict__ dst,
                                                   int* __restrict__ cnt) {
  int e = blockIdx.x * 256 + threadIdx.x;
  if (e < NEDGES) atomicAdd(&cnt[dst[e]], 1);
}

__global__ __launch_bounds__(1024) void bsum_kernel(const int* __restrict__ cnt,
                                                    int* __restrict__ bsums) {
  __shared__ int red[16];
  const int t = threadIdx.x;
  const int i = blockIdx.x * 1024 + t;
  int v = (i < NNODES) ? cnt[i] : 0;
#pragma unroll
  for (int off = 32; off > 0; off >>= 1) v += __shfl_down(v, off, 64);
  if ((t & 63) == 0) red[t >> 6] = v;
  __syncthreads();
  if (t < 16) {
    int s = red[t];
#pragma unroll
    for (int off = 8; off > 0; off >>= 1) s += __shfl_down(s, off, 16);
    if (t == 0) bsums[blockIdx.x] = s;
  }
}

__global__ __launch_bounds__(128) void bscan_kernel(int* __restrict__ bsums,
                                                    int* __restrict__ offs) {
  __shared__ int s[128];
  const int t = threadIdx.x;
  int v = (t < NBLK_SCAN) ? bsums[t] : 0;
  s[t] = v;
  __syncthreads();
  for (int off = 1; off < 128; off <<= 1) {
    int u = (t >= off) ? s[t - off] : 0;
    __syncthreads();
    s[t] += u;
    __syncthreads();
  }
  if (t < NBLK_SCAN) bsums[t] = s[t] - v;
  if (t == NBLK_SCAN - 1) offs[NNODES] = s[t];
}

__global__ __launch_bounds__(1024) void offs_kernel(int* __restrict__ cnt,
                                                    const int* __restrict__ bsums,
                                                    int* __restrict__ offs) {
  __shared__ int s[1024];
  const int t = threadIdx.x;
  const int i = blockIdx.x * 1024 + t;
  int v = (i < NNODES) ? cnt[i] : 0;
  s[t] = v;
  __syncthreads();
  for (int off = 1; off < 1024; off <<= 1) {
    int u = (t >= off) ? s[t - off] : 0;
    __syncthreads();
    s[t] += u;
    __syncthreads();
  }
  int excl = s[t] - v + bsums[blockIdx.x];
  if (i < NNODES) {
    offs[i] = excl;
    cnt[i] = excl;  // cursor init for fill_kernel
  }
}

__global__ __launch_bounds__(256) void fill_kernel(const int* __restrict__ src,
                                                   const int* __restrict__ dst,
                                                   int* __restrict__ cursor,
                                                   int* __restrict__ esrc) {
  int e = blockIdx.x * 256 + threadIdx.x;
  if (e >= NEDGES) return;
  int pos = atomicAdd(&cursor[dst[e]], 1);
  esrc[pos] = src[e];
}

// ---------------- gather-aggregate (unchanged) ----------------
__global__ __launch_bounds__(256) void agg_kernel(const float* __restrict__ nf,
                                                  const int* __restrict__ offs,
                                                  const int* __restrict__ esrc,
                                                  float* __restrict__ agg) {
  const int t = threadIdx.x;
  const int node = blockIdx.x * 8 + (t >> 5);
  const int c4 = (t & 31) << 2;
  const int beg = offs[node];
  const int end = offs[node + 1];
  float4 a0 = make_float4(0.f, 0.f, 0.f, 0.f);
  float4 a1 = make_float4(0.f, 0.f, 0.f, 0.f);
  int i = beg;
  for (; i + 1 < end; i += 2) {
    int s0 = esrc[i];
    int s1 = esrc[i + 1];
    float4 v0 = *(const float4*)&nf[s0 * DD + c4];
    float4 v1 = *(const float4*)&nf[s1 * DD + c4];
    a0.x += v0.x; a0.y += v0.y; a0.z += v0.z; a0.w += v0.w;
    a1.x += v1.x; a1.y += v1.y; a1.z += v1.z; a1.w += v1.w;
  }
  if (i < end) {
    int s0 = esrc[i];
    float4 v0 = *(const float4*)&nf[s0 * DD + c4];
    a0.x += v0.x; a0.y += v0.y; a0.z += v0.z; a0.w += v0.w;
  }
  a0.x += a1.x; a0.y += a1.y; a0.z += a1.z; a0.w += a1.w;
  *(float4*)&agg[node * DD + c4] = a0;
}

// ---------------- weight prep: fp32 -> split-bf16, tile-packed ----------------
__global__ __launch_bounds__(256) void wprep_kernel(const float* __restrict__ W1,
                                                    const float* __restrict__ W2,
                                                    const float* __restrict__ W3,
                                                    ushort* __restrict__ wt) {
  int tid = blockIdx.x * 256 + threadIdx.x;  // 65536 total
  const float* W;
  int dstHi, dstLo, k, col;
  if (tid < 32768) {  // layer 1, K=256: tiles = c16*8 + kk, c16<8, kk<8
    int j = tid & 7, l = (tid >> 3) & 63, tile = tid >> 9;
    int kk = tile & 7, c16 = tile >> 3;
    k = kk * 32 + (l >> 4) * 8 + j;
    col = c16 * 16 + (l & 15);
    W = W1;
    dstHi = WT1HI + tid;
    dstLo = WT1LO + tid;
  } else {  // layers 2/3, K=128: tiles = c16*4 + kk, c16<8, kk<4
    int t2 = tid - 32768;
    int which = t2 >> 14;
    int t1 = t2 & 16383;
    int j = t1 & 7, l = (t1 >> 3) & 63, tile = t1 >> 9;
    int kk = tile & 3, c16 = tile >> 2;
    k = kk * 32 + (l >> 4) * 8 + j;
    col = c16 * 16 + (l & 15);
    W = which ? W3 : W2;
    dstHi = (which ? WT3HI : WT2HI) + t1;
    dstLo = (which ? WT3LO : WT2LO) + t1;
  }
  ushort hi, lo;
  bf16_split(W[k * DD + col], hi, lo);
  wt[dstHi] = hi;
  wt[dstLo] = lo;
}

// ---------------- MFMA MLP v3 ----------------
// Block = 64 rows x 128 cols, 4 waves. Wave w: wr=w&1 (32-row half),
// wc=w>>1 (64-col half). Per wave: 2 row-tiles x 4 col-tiles of 16x16,
// acc[2][4]. A-frags read straight from global (L2/L3-hot agg/nf) or
// swizzled LDS H; B-frags are single coalesced 1KB loads from the
// tile-packed tables (VMEM:MFMA = 1:3).
// Frag maps (verified R1): A: lane l = A[row=l&15][k=(l>>4)*8+j];
// B: lane l = B[k=(l>>4)*8+j][col=l&15]; D: lane l reg i = [(l>>4)*4+i][l&15].

__device__ __forceinline__ void store_h(ushort* Hh, ushort* Hl,
                                        const float* __restrict__ b,
                                        int wr, int wc, int l15, int lhi,
                                        f32x4 acc[2][4]) {
#pragma unroll
  for (int rt = 0; rt < 2; ++rt) {
#pragma unroll
    for (int ct = 0; ct < 4; ++ct) {
      int col = wc * 64 + ct * 16 + l15;
      float bias = b[col];
#pragma unroll
      for (int i = 0; i < 4; ++i) {
        int row = wr * 32 + rt * 16 + lhi * 4 + i;
        float v = fmaxf(acc[rt][ct][i] + bias, 0.f);
        ushort h, l;
        bf16_split(v, h, l);
        int byte = (row * 256 + col * 2) ^ ((row & 7) << 4);
        *(ushort*)((char*)Hh + byte) = h;
        *(ushort*)((char*)Hl + byte) = l;
      }
    }
  }
}

// one 32-k step of layer 1 with A from global memory
__device__ __forceinline__ void l1_step(const float* __restrict__ srcb,
                                        const ushort* __restrict__ wt,
                                        int kkTile, int kOff, const int rowA[2],
                                        int wc, int lane, int lhi,
                                        f32x4 acc[2][4]) {
  short8 ahi[2], alo[2];
#pragma unroll
  for (int rt = 0; rt < 2; ++rt) {
    const float* p = srcb + rowA[rt] * DD + kOff + lhi * 8;
    float4 v0 = *(const float4*)p;
    float4 v1 = *(const float4*)(p + 4);
    split8(v0, v1, ahi[rt], alo[rt]);
  }
#pragma unroll
  for (int ct = 0; ct < 4; ++ct) {
    int tb = ((wc * 4 + ct) * 8 + kkTile) * 512 + lane * 8;
    short8 bhi = *(const short8*)&wt[WT1HI + tb];
    short8 blo = *(const short8*)&wt[WT1LO + tb];
#pragma unroll
    for (int rt = 0; rt < 2; ++rt) {
      acc[rt][ct] = __builtin_amdgcn_mfma_f32_16x16x32_bf16(ahi[rt], bhi, acc[rt][ct], 0, 0, 0);
      acc[rt][ct] = __builtin_amdgcn_mfma_f32_16x16x32_bf16(ahi[rt], blo, acc[rt][ct], 0, 0, 0);
      acc[rt][ct] = __builtin_amdgcn_mfma_f32_16x16x32_bf16(alo[rt], bhi, acc[rt][ct], 0, 0, 0);
    }
  }
}

// layers 2/3: A from swizzled LDS, K=128 (4 k-steps)
__device__ __forceinline__ void layer_lds(const ushort* Hh, const ushort* Hl,
                                          const ushort* __restrict__ WhiT,
                                          const ushort* __restrict__ WloT,
                                          int wr, int wc, int lane, int l15,
                                          int lhi, f32x4 acc[2][4]) {
#pragma unroll 2
  for (int kk = 0; kk < 4; ++kk) {
    short8 ahi[2], alo[2];
#pragma unroll
    for (int rt = 0; rt < 2; ++rt) {
      int row = wr * 32 + rt * 16 + l15;
      int byte = (row * 256 + kk * 64 + lhi * 16) ^ ((row & 7) << 4);
      ahi[rt] = *(const short8*)((const char*)Hh + byte);
      alo[rt] = *(const short8*)((const char*)Hl + byte);
    }
#pragma unroll
    for (int ct = 0; ct < 4; ++ct) {
      int tb = ((wc * 4 + ct) * 4 + kk) * 512 + lane * 8;
      short8 bhi = *(const short8*)&WhiT[tb];
      short8 blo = *(const short8*)&WloT[tb];
#pragma unroll
      for (int rt = 0; rt < 2; ++rt) {
        acc[rt][ct] = __builtin_amdgcn_mfma_f32_16x16x32_bf16(ahi[rt], bhi, acc[rt][ct], 0, 0, 0);
        acc[rt][ct] = __builtin_amdgcn_mfma_f32_16x16x32_bf16(ahi[rt], blo, acc[rt][ct], 0, 0, 0);
        acc[rt][ct] = __builtin_amdgcn_mfma_f32_16x16x32_bf16(alo[rt], bhi, acc[rt][ct], 0, 0, 0);
      }
    }
  }
}

__global__ __launch_bounds__(256, 4) void mlp_kernel(const float* __restrict__ agg,
                                                     const float* __restrict__ nf,
                                                     const ushort* __restrict__ wt,
                                                     const float* __restrict__ b1,
                                                     const float* __restrict__ b2,
                                                     const float* __restrict__ b3,
                                                     float* __restrict__ out) {
  // Hhi[64][128] | Hlo[64][128] ushort = 32KB; H2 reuses the same region.
  __shared__ ushort smem[16384];
  ushort* Hhi = smem;
  ushort* Hlo = smem + 8192;

  const int t = threadIdx.x;
  const int lane = t & 63;
  const int w = t >> 6;
  const int wr = w & 1;
  const int wc = w >> 1;
  const int l15 = lane & 15;
  const int lhi = lane >> 4;
  const int base = blockIdx.x * BM;

  // A-frag rows for this lane (clamped; stores are guarded, and the clamp
  // target row stays within this block's own range so the out-aliasing of
  // agg remains safe).
  int rowA[2];
  {
    int r0 = base + wr * 32 + l15;
    rowA[0] = min(r0, NNODES - 1);
    rowA[1] = min(r0 + 16, NNODES - 1);
  }

  const f32x4 z = {0.f, 0.f, 0.f, 0.f};
  f32x4 acc[2][4];

  // ---- layer 1: X = [agg | nf], A straight from global ----
#pragma unroll
  for (int rt = 0; rt < 2; ++rt)
#pragma unroll
    for (int ct = 0; ct < 4; ++ct) acc[rt][ct] = z;
#pragma unroll 2
  for (int kk = 0; kk < 4; ++kk)
    l1_step(agg, wt, kk, kk * 32, rowA, wc, lane, lhi, acc);
#pragma unroll 2
  for (int kk = 0; kk < 4; ++kk)
    l1_step(nf, wt, kk + 4, kk * 32, rowA, wc, lane, lhi, acc);
  store_h(Hhi, Hlo, b1, wr, wc, l15, lhi, acc);
  __syncthreads();

  // ---- layer 2 ----
#pragma unroll
  for (int rt = 0; rt < 2; ++rt)
#pragma unroll
    for (int ct = 0; ct < 4; ++ct) acc[rt][ct] = z;
  layer_lds(Hhi, Hlo, wt + WT2HI, wt + WT2LO, wr, wc, lane, l15, lhi, acc);
  __syncthreads();  // all reads of H1 done before overwrite
  store_h(Hhi, Hlo, b2, wr, wc, l15, lhi, acc);
  __syncthreads();

  // ---- layer 3 ----
#pragma unroll
  for (int rt = 0; rt < 2; ++rt)
#pragma unroll
    for (int ct = 0; ct < 4; ++ct) acc[rt][ct] = z;
  layer_lds(Hhi, Hlo, wt + WT3HI, wt + WT3LO, wr, wc, lane, l15, lhi, acc);
#pragma unroll
  for (int rt = 0; rt < 2; ++rt) {
#pragma unroll
    for (int ct = 0; ct < 4; ++ct) {
      int col = wc * 64 + ct * 16 + l15;
      float bias = b3[col];
#pragma unroll
      for (int i = 0; i < 4; ++i) {
        int row = base + wr * 32 + rt * 16 + lhi * 4 + i;
        if (row < NNODES) out[row * DD + col] = acc[rt][ct][i] + bias;
      }
    }
  }
}

extern "C" void kernel_launch(void* const* d_in, const int* in_sizes, int n_in,
                              void* d_out, int out_size, void* d_ws, size_t ws_size,
                              hipStream_t stream) {
  const float* nf = (const float*)d_in[0];
  const int* src = (const int*)d_in[1];
  const int* dst = (const int*)d_in[2];
  const float* W1 = (const float*)d_in[3];
  const float* b1 = (const float*)d_in[4];
  const float* W2 = (const float*)d_in[5];
  const float* b2 = (const float*)d_in[6];
  const float* W3 = (const float*)d_in[7];
  const float* b3 = (const float*)d_in[8];
  float* out = (float*)d_out;

  int* wsi = (int*)d_ws;
  int* cnt = wsi + WS_CNT;      // cursor, then weight tables
  int* bsums = wsi + WS_BSUMS;  // 98 ints (slack)
  int* offs = wsi + WS_OFFS;    // 100001
  int* esrc = wsi + WS_ESRC;    // 1600000
  ushort* wt = (ushort*)cnt;    // 131072 ushorts (256KB) — safe after fill

  // agg aliases d_out: agg_kernel writes each row once; mlp_kernel reads only
  // its own block's rows before (guarded) overwriting them.
  float* agg = out;

  hipMemsetAsync(cnt, 0, NNODES * sizeof(int), stream);
  hist_kernel<<<(NEDGES + 255) / 256, 256, 0, stream>>>(dst, cnt);
  bsum_kernel<<<NBLK_SCAN, 1024, 0, stream>>>(cnt, bsums);
  bscan_kernel<<<1, 128, 0, stream>>>(bsums, offs);
  offs_kernel<<<NBLK_SCAN, 1024, 0, stream>>>(cnt, bsums, offs);
  fill_kernel<<<(NEDGES + 255) / 256, 256, 0, stream>>>(src, dst, cnt, esrc);
  // cnt region is dead from here on — convert weights into it
  wprep_kernel<<<256, 256, 0, stream>>>(W1, W2, W3, wt);
  agg_kernel<<<NNODES / 8, 256, 0, stream>>>(nf, offs, esrc, agg);
  mlp_kernel<<<NBLK_MLP, 256, 0, stream>>>(agg, nf, wt, b1, b2, b3, out);
}

// Round 4
// 321.395 us; speedup vs baseline: 2.3215x; 1.2395x over previous
//
#include <hip/hip_runtime.h>

#define NNODES 100000
#define NEDGES 1600000
#define DD 128
#define BM 64
#define NBLK_SCAN 98                       // ceil(NNODES / 1024); == coarse buckets
#define NBLK_MLP ((NNODES + BM - 1) / BM)  // 1563
#define CAP 32                             // bin1 staging entries per bucket (128B)
#define BIN1_WGS 200
#define BIN1_EPW 8192                      // edges per workgroup (8 rounds x 1024)

// ---------------- workspace layout (ints) ----------------
// cnt[100000] | bsums[98] gcur[98] (slack) | offs[100001] | esrc[1600000]
// cnt region is dead after offs_kernel; wprep reuses it for tile-packed
// split-bf16 weight tables. bin1's coarse-binned edge buffer lives in `out`
// scratch (dead until agg rewrites it).
#define WS_CNT 0
#define WS_BSUMS 100000
#define WS_GCUR 100128
#define WS_OFFS 100352
#define WS_ESRC 201216

// ushort offsets inside the cnt region (tile-packed weight tables)
#define WT1HI 0        // K=256: 8 c16 x 8 kk tiles, 1KB/tile
#define WT1LO 32768
#define WT2HI 65536    // K=128: 8 x 4 tiles
#define WT2LO 81920
#define WT3HI 98304
#define WT3LO 114688

typedef __attribute__((ext_vector_type(8))) short short8;  // 8 bf16
typedef __attribute__((ext_vector_type(4))) float f32x4;

// x ~= hi + lo, both bf16 (RNE). hi*whi + hi*wlo + lo*whi gives ~2^-16 rel err.
__device__ __forceinline__ void bf16_split(float x, ushort& hi, ushort& lo) {
  unsigned u = __float_as_uint(x);
  ushort h = (ushort)((u + 0x7FFFu + ((u >> 16) & 1u)) >> 16);
  float r = x - __uint_as_float(((unsigned)h) << 16);  // exact in fp32
  unsigned v = __float_as_uint(r);
  ushort l = (ushort)((v + 0x7FFFu + ((v >> 16) & 1u)) >> 16);
  hi = h;
  lo = l;
}

__device__ __forceinline__ void split8(const float4 v0, const float4 v1,
                                       short8& hi, short8& lo) {
  float x[8] = {v0.x, v0.y, v0.z, v0.w, v1.x, v1.y, v1.z, v1.w};
#pragma unroll
  for (int j = 0; j < 8; ++j) {
    ushort h, l;
    bf16_split(x[j], h, l);
    hi[j] = (short)h;
    lo[j] = (short)l;
  }
}

// ---------------- CSR build ----------------
__global__ __launch_bounds__(256) void hist_kernel(const int* __restrict__ dst,
                                                   int* __restrict__ cnt) {
  int e = blockIdx.x * 256 + threadIdx.x;
  if (e < NEDGES) atomicAdd(&cnt[dst[e]], 1);
}

__global__ __launch_bounds__(1024) void bsum_kernel(const int* __restrict__ cnt,
                                                    int* __restrict__ bsums) {
  __shared__ int red[16];
  const int t = threadIdx.x;
  const int i = blockIdx.x * 1024 + t;
  int v = (i < NNODES) ? cnt[i] : 0;
#pragma unroll
  for (int off = 32; off > 0; off >>= 1) v += __shfl_down(v, off, 64);
  if ((t & 63) == 0) red[t >> 6] = v;
  __syncthreads();
  if (t < 16) {
    int s = red[t];
#pragma unroll
    for (int off = 8; off > 0; off >>= 1) s += __shfl_down(s, off, 16);
    if (t == 0) bsums[blockIdx.x] = s;
  }
}

// Exclusive scan of 98 block sums; also initializes bin1's coarse cursors
// (coarse bucket == scan block: 1024 nodes).
__global__ __launch_bounds__(128) void bscan_kernel(int* __restrict__ bsums,
                                                    int* __restrict__ gcur,
                                                    int* __restrict__ offs) {
  __shared__ int s[128];
  const int t = threadIdx.x;
  int v = (t < NBLK_SCAN) ? bsums[t] : 0;
  s[t] = v;
  __syncthreads();
  for (int off = 1; off < 128; off <<= 1) {
    int u = (t >= off) ? s[t - off] : 0;
    __syncthreads();
    s[t] += u;
    __syncthreads();
  }
  if (t < NBLK_SCAN) {
    int excl = s[t] - v;
    bsums[t] = excl;
    gcur[t] = excl;
  }
  if (t == NBLK_SCAN - 1) offs[NNODES] = s[t];
}

__global__ __launch_bounds__(1024) void offs_kernel(const int* __restrict__ cnt,
                                                    const int* __restrict__ bsums,
                                                    int* __restrict__ offs) {
  __shared__ int s[1024];
  const int t = threadIdx.x;
  const int i = blockIdx.x * 1024 + t;
  int v = (i < NNODES) ? cnt[i] : 0;
  s[t] = v;
  __syncthreads();
  for (int off = 1; off < 1024; off <<= 1) {
    int u = (t >= off) ? s[t - off] : 0;
    __syncthreads();
    s[t] += u;
    __syncthreads();
  }
  if (i < NNODES) offs[i] = s[t] - v + bsums[blockIdx.x];
}

// ---------------- bin1: coarse-bucket scatter with LDS line-coalesced flush ----
// Entry: (dst & 1023) << 17 | src  (src < 2^17). Bucket = dst >> 10 (98 buckets).
// Appends into ebuf segments [bsums[c], ...) via global cursor gcur[c];
// all ebuf writes are contiguous 128B (CAP) runs from a single thread.
__global__ __launch_bounds__(256) void bin1_kernel(const int* __restrict__ src,
                                                   const int* __restrict__ dst,
                                                   int* __restrict__ gcur,
                                                   unsigned* __restrict__ ebuf) {
  __shared__ unsigned stage[NBLK_SCAN][CAP];
  __shared__ int scnt[NBLK_SCAN];
  const int t = threadIdx.x;
  for (int i = t; i < NBLK_SCAN; i += 256) scnt[i] = 0;
  __syncthreads();
  const int e0 = blockIdx.x * BIN1_EPW;
  for (int r = 0; r < BIN1_EPW / 1024; ++r) {
    unsigned item[4];
    int buck[4];
    int pend[4];
#pragma unroll
    for (int j = 0; j < 4; ++j) {
      pend[j] = 0;
      int e = e0 + r * 1024 + j * 256 + t;
      if (e < NEDGES) {
        int d = dst[e];
        int s = src[e];
        buck[j] = d >> 10;
        item[j] = ((unsigned)(d & 1023) << 17) | (unsigned)s;
        int p = atomicAdd(&scnt[buck[j]], 1);
        if (p < CAP)
          stage[buck[j]][p] = item[j];
        else
          pend[j] = 1;
      }
    }
    // flush full buckets; retry pendings until none remain (uniform loop)
    int pendLeft;
    do {
      __syncthreads();  // stage writes visible to flushers
      if (t < NBLK_SCAN && scnt[t] >= CAP) {
        int base = atomicAdd(&gcur[t], CAP);
        for (int q = 0; q < CAP; ++q) ebuf[base + q] = stage[t][q];
        scnt[t] = 0;  // phantom counts beyond CAP will re-insert below
      }
      __syncthreads();  // resets visible before retry
      int mypend = 0;
#pragma unroll
      for (int j = 0; j < 4; ++j) {
        if (pend[j]) {
          int p = atomicAdd(&scnt[buck[j]], 1);
          if (p < CAP) {
            stage[buck[j]][p] = item[j];
            pend[j] = 0;
          } else {
            mypend = 1;
          }
        }
      }
      pendLeft = __syncthreads_count(mypend);
    } while (pendLeft > 0);
  }
  // final partial flush
  __syncthreads();
  if (t < NBLK_SCAN) {
    int n = scnt[t];  // < CAP here (full ones were flushed in last do-loop)
    if (n > 0) {
      int base = atomicAdd(&gcur[t], n);
      for (int q = 0; q < n; ++q) ebuf[base + q] = stage[t][q];
    }
  }
}

// ---------------- bin2: exact CSR scatter within one coarse bucket ----------
// Scatter window is this bucket's ~65KB esrc range, written by one CU in a
// short window -> lines merge in L2, ~1x write amplification.
__global__ __launch_bounds__(1024) void bin2_kernel(const unsigned* __restrict__ ebuf,
                                                    const int* __restrict__ offs,
                                                    int* __restrict__ esrc) {
  __shared__ int cur[1024];
  const int t = threadIdx.x;
  const int c = blockIdx.x;
  const int nbase = c << 10;
  const int nend = min(nbase + 1024, NNODES);
  if (t < nend - nbase) cur[t] = offs[nbase + t];
  __syncthreads();
  const int segb = offs[nbase];
  const int sege = offs[nend];
  for (int i = segb + t; i < sege; i += 1024) {
    unsigned v = ebuf[i];
    int dl = (int)(v >> 17);
    int s = (int)(v & 0x1FFFFu);
    int p = atomicAdd(&cur[dl], 1);
    esrc[p] = s;
  }
}

// ---------------- gather-aggregate (unchanged) ----------------
__global__ __launch_bounds__(256) void agg_kernel(const float* __restrict__ nf,
                                                  const int* __restrict__ offs,
                                                  const int* __restrict__ esrc,
                                                  float* __restrict__ agg) {
  const int t = threadIdx.x;
  const int node = blockIdx.x * 8 + (t >> 5);
  const int c4 = (t & 31) << 2;
  const int beg = offs[node];
  const int end = offs[node + 1];
  float4 a0 = make_float4(0.f, 0.f, 0.f, 0.f);
  float4 a1 = make_float4(0.f, 0.f, 0.f, 0.f);
  int i = beg;
  for (; i + 1 < end; i += 2) {
    int s0 = esrc[i];
    int s1 = esrc[i + 1];
    float4 v0 = *(const float4*)&nf[s0 * DD + c4];
    float4 v1 = *(const float4*)&nf[s1 * DD + c4];
    a0.x += v0.x; a0.y += v0.y; a0.z += v0.z; a0.w += v0.w;
    a1.x += v1.x; a1.y += v1.y; a1.z += v1.z; a1.w += v1.w;
  }
  if (i < end) {
    int s0 = esrc[i];
    float4 v0 = *(const float4*)&nf[s0 * DD + c4];
    a0.x += v0.x; a0.y += v0.y; a0.z += v0.z; a0.w += v0.w;
  }
  a0.x += a1.x; a0.y += a1.y; a0.z += a1.z; a0.w += a1.w;
  *(float4*)&agg[node * DD + c4] = a0;
}

// ---------------- weight prep: fp32 -> split-bf16, tile-packed ----------------
__global__ __launch_bounds__(256) void wprep_kernel(const float* __restrict__ W1,
                                                    const float* __restrict__ W2,
                                                    const float* __restrict__ W3,
                                                    ushort* __restrict__ wt) {
  int tid = blockIdx.x * 256 + threadIdx.x;  // 65536 total
  const float* W;
  int dstHi, dstLo, k, col;
  if (tid < 32768) {  // layer 1, K=256: tiles = c16*8 + kk
    int j = tid & 7, l = (tid >> 3) & 63, tile = tid >> 9;
    int kk = tile & 7, c16 = tile >> 3;
    k = kk * 32 + (l >> 4) * 8 + j;
    col = c16 * 16 + (l & 15);
    W = W1;
    dstHi = WT1HI + tid;
    dstLo = WT1LO + tid;
  } else {  // layers 2/3, K=128: tiles = c16*4 + kk
    int t2 = tid - 32768;
    int which = t2 >> 14;
    int t1 = t2 & 16383;
    int j = t1 & 7, l = (t1 >> 3) & 63, tile = t1 >> 9;
    int kk = tile & 3, c16 = tile >> 2;
    k = kk * 32 + (l >> 4) * 8 + j;
    col = c16 * 16 + (l & 15);
    W = which ? W3 : W2;
    dstHi = (which ? WT3HI : WT2HI) + t1;
    dstLo = (which ? WT3LO : WT2LO) + t1;
  }
  ushort hi, lo;
  bf16_split(W[k * DD + col], hi, lo);
  wt[dstHi] = hi;
  wt[dstLo] = lo;
}

// ---------------- MFMA MLP (unchanged from R3) ----------------
__device__ __forceinline__ void store_h(ushort* Hh, ushort* Hl,
                                        const float* __restrict__ b,
                                        int wr, int wc, int l15, int lhi,
                                        f32x4 acc[2][4]) {
#pragma unroll
  for (int rt = 0; rt < 2; ++rt) {
#pragma unroll
    for (int ct = 0; ct < 4; ++ct) {
      int col = wc * 64 + ct * 16 + l15;
      float bias = b[col];
#pragma unroll
      for (int i = 0; i < 4; ++i) {
        int row = wr * 32 + rt * 16 + lhi * 4 + i;
        float v = fmaxf(acc[rt][ct][i] + bias, 0.f);
        ushort h, l;
        bf16_split(v, h, l);
        int byte = (row * 256 + col * 2) ^ ((row & 7) << 4);
        *(ushort*)((char*)Hh + byte) = h;
        *(ushort*)((char*)Hl + byte) = l;
      }
    }
  }
}

__device__ __forceinline__ void l1_step(const float* __restrict__ srcb,
                                        const ushort* __restrict__ wt,
                                        int kkTile, int kOff, const int rowA[2],
                                        int wc, int lane, int lhi,
                                        f32x4 acc[2][4]) {
  short8 ahi[2], alo[2];
#pragma unroll
  for (int rt = 0; rt < 2; ++rt) {
    const float* p = srcb + rowA[rt] * DD + kOff + lhi * 8;
    float4 v0 = *(const float4*)p;
    float4 v1 = *(const float4*)(p + 4);
    split8(v0, v1, ahi[rt], alo[rt]);
  }
#pragma unroll
  for (int ct = 0; ct < 4; ++ct) {
    int tb = ((wc * 4 + ct) * 8 + kkTile) * 512 + lane * 8;
    short8 bhi = *(const short8*)&wt[WT1HI + tb];
    short8 blo = *(const short8*)&wt[WT1LO + tb];
#pragma unroll
    for (int rt = 0; rt < 2; ++rt) {
      acc[rt][ct] = __builtin_amdgcn_mfma_f32_16x16x32_bf16(ahi[rt], bhi, acc[rt][ct], 0, 0, 0);
      acc[rt][ct] = __builtin_amdgcn_mfma_f32_16x16x32_bf16(ahi[rt], blo, acc[rt][ct], 0, 0, 0);
      acc[rt][ct] = __builtin_amdgcn_mfma_f32_16x16x32_bf16(alo[rt], bhi, acc[rt][ct], 0, 0, 0);
    }
  }
}

__device__ __forceinline__ void layer_lds(const ushort* Hh, const ushort* Hl,
                                          const ushort* __restrict__ WhiT,
                                          const ushort* __restrict__ WloT,
                                          int wr, int wc, int lane, int l15,
                                          int lhi, f32x4 acc[2][4]) {
#pragma unroll 2
  for (int kk = 0; kk < 4; ++kk) {
    short8 ahi[2], alo[2];
#pragma unroll
    for (int rt = 0; rt < 2; ++rt) {
      int row = wr * 32 + rt * 16 + l15;
      int byte = (row * 256 + kk * 64 + lhi * 16) ^ ((row & 7) << 4);
      ahi[rt] = *(const short8*)((const char*)Hh + byte);
      alo[rt] = *(const short8*)((const char*)Hl + byte);
    }
#pragma unroll
    for (int ct = 0; ct < 4; ++ct) {
      int tb = ((wc * 4 + ct) * 4 + kk) * 512 + lane * 8;
      short8 bhi = *(const short8*)&WhiT[tb];
      short8 blo = *(const short8*)&WloT[tb];
#pragma unroll
      for (int rt = 0; rt < 2; ++rt) {
        acc[rt][ct] = __builtin_amdgcn_mfma_f32_16x16x32_bf16(ahi[rt], bhi, acc[rt][ct], 0, 0, 0);
        acc[rt][ct] = __builtin_amdgcn_mfma_f32_16x16x32_bf16(ahi[rt], blo, acc[rt][ct], 0, 0, 0);
        acc[rt][ct] = __builtin_amdgcn_mfma_f32_16x16x32_bf16(alo[rt], bhi, acc[rt][ct], 0, 0, 0);
      }
    }
  }
}

__global__ __launch_bounds__(256, 4) void mlp_kernel(const float* __restrict__ agg,
                                                     const float* __restrict__ nf,
                                                     const ushort* __restrict__ wt,
                                                     const float* __restrict__ b1,
                                                     const float* __restrict__ b2,
                                                     const float* __restrict__ b3,
                                                     float* __restrict__ out) {
  __shared__ ushort smem[16384];
  ushort* Hhi = smem;
  ushort* Hlo = smem + 8192;

  const int t = threadIdx.x;
  const int lane = t & 63;
  const int w = t >> 6;
  const int wr = w & 1;
  const int wc = w >> 1;
  const int l15 = lane & 15;
  const int lhi = lane >> 4;
  const int base = blockIdx.x * BM;

  int rowA[2];
  {
    int r0 = base + wr * 32 + l15;
    rowA[0] = min(r0, NNODES - 1);
    rowA[1] = min(r0 + 16, NNODES - 1);
  }

  const f32x4 z = {0.f, 0.f, 0.f, 0.f};
  f32x4 acc[2][4];

#pragma unroll
  for (int rt = 0; rt < 2; ++rt)
#pragma unroll
    for (int ct = 0; ct < 4; ++ct) acc[rt][ct] = z;
#pragma unroll 2
  for (int kk = 0; kk < 4; ++kk)
    l1_step(agg, wt, kk, kk * 32, rowA, wc, lane, lhi, acc);
#pragma unroll 2
  for (int kk = 0; kk < 4; ++kk)
    l1_step(nf, wt, kk + 4, kk * 32, rowA, wc, lane, lhi, acc);
  store_h(Hhi, Hlo, b1, wr, wc, l15, lhi, acc);
  __syncthreads();

#pragma unroll
  for (int rt = 0; rt < 2; ++rt)
#pragma unroll
    for (int ct = 0; ct < 4; ++ct) acc[rt][ct] = z;
  layer_lds(Hhi, Hlo, wt + WT2HI, wt + WT2LO, wr, wc, lane, l15, lhi, acc);
  __syncthreads();
  store_h(Hhi, Hlo, b2, wr, wc, l15, lhi, acc);
  __syncthreads();

#pragma unroll
  for (int rt = 0; rt < 2; ++rt)
#pragma unroll
    for (int ct = 0; ct < 4; ++ct) acc[rt][ct] = z;
  layer_lds(Hhi, Hlo, wt + WT3HI, wt + WT3LO, wr, wc, lane, l15, lhi, acc);
#pragma unroll
  for (int rt = 0; rt < 2; ++rt) {
#pragma unroll
    for (int ct = 0; ct < 4; ++ct) {
      int col = wc * 64 + ct * 16 + l15;
      float bias = b3[col];
#pragma unroll
      for (int i = 0; i < 4; ++i) {
        int row = base + wr * 32 + rt * 16 + lhi * 4 + i;
        if (row < NNODES) out[row * DD + col] = acc[rt][ct][i] + bias;
      }
    }
  }
}

extern "C" void kernel_launch(void* const* d_in, const int* in_sizes, int n_in,
                              void* d_out, int out_size, void* d_ws, size_t ws_size,
                              hipStream_t stream) {
  const float* nf = (const float*)d_in[0];
  const int* src = (const int*)d_in[1];
  const int* dst = (const int*)d_in[2];
  const float* W1 = (const float*)d_in[3];
  const float* b1 = (const float*)d_in[4];
  const float* W2 = (const float*)d_in[5];
  const float* b2 = (const float*)d_in[6];
  const float* W3 = (const float*)d_in[7];
  const float* b3 = (const float*)d_in[8];
  float* out = (float*)d_out;

  int* wsi = (int*)d_ws;
  int* cnt = wsi + WS_CNT;      // histogram counts, later weight tables
  int* bsums = wsi + WS_BSUMS;  // 98 ints: coarse segment bases
  int* gcur = wsi + WS_GCUR;    // 98 ints: bin1 append cursors
  int* offs = wsi + WS_OFFS;    // 100001
  int* esrc = wsi + WS_ESRC;    // 1600000
  ushort* wt = (ushort*)cnt;    // 256KB weight tables — safe after offs_kernel

  // Scratch carved from `out`: bin1's coarse-binned edge buffer (6.4MB).
  // Dead after bin2; agg_kernel later rewrites every row of out.
  unsigned* ebuf = (unsigned*)out;
  float* agg = out;  // agg aliases d_out (same discipline as before)

  hipMemsetAsync(cnt, 0, NNODES * sizeof(int), stream);
  hist_kernel<<<(NEDGES + 255) / 256, 256, 0, stream>>>(dst, cnt);
  bsum_kernel<<<NBLK_SCAN, 1024, 0, stream>>>(cnt, bsums);
  bscan_kernel<<<1, 128, 0, stream>>>(bsums, gcur, offs);
  offs_kernel<<<NBLK_SCAN, 1024, 0, stream>>>(cnt, bsums, offs);
  bin1_kernel<<<BIN1_WGS, 256, 0, stream>>>(src, dst, gcur, ebuf);
  bin2_kernel<<<NBLK_SCAN, 1024, 0, stream>>>(ebuf, offs, esrc);
  // cnt region dead from here — convert weights into it
  wprep_kernel<<<256, 256, 0, stream>>>(W1, W2, W3, wt);
  agg_kernel<<<NNODES / 8, 256, 0, stream>>>(nf, offs, esrc, agg);
  mlp_kernel<<<NBLK_MLP, 256, 0, stream>>>(agg, nf, wt, b1, b2, b3, out);
}

// Round 5
// 253.890 us; speedup vs baseline: 2.9388x; 1.2659x over previous
//
#include <hip/hip_runtime.h>

#define NNODES 100000
#define NEDGES 1600000
#define DD 128
#define BM 64
#define NBUCK 98                           // coarse buckets of 1024 nodes
#define NBLK_MLP ((NNODES + BM - 1) / BM)  // 1563
#define CAP 32                             // bin1 LDS staging entries per bucket
#define CAPB 20480                         // fixed ebuf capacity per bucket (mean 16327, +32 sigma)
#define BIN1_WGS 200
#define BIN1_EPW 8192                      // edges per workgroup (8 rounds x 1024)

// ---------------- workspace layout (ints) ----------------
// [0,100000): weight tables (ushort view) — nothing else uses this region now
// [100000,100098): gcur (bucket entry counts / append cursors)
// [100128,100226): bbase (exclusive bucket bases)
// [100352,200353): offs
// [201216,1801216): esrc
#define WS_GCUR 100000
#define WS_BBASE 100128
#define WS_OFFS 100352
#define WS_ESRC 201216

// ushort offsets inside the weight-table region (tile-packed)
#define WT1HI 0        // K=256: 8 c16 x 8 kk tiles, 1KB/tile
#define WT1LO 32768
#define WT2HI 65536    // K=128: 8 x 4 tiles
#define WT2LO 81920
#define WT3HI 98304
#define WT3LO 114688

typedef __attribute__((ext_vector_type(8))) short short8;  // 8 bf16
typedef __attribute__((ext_vector_type(4))) float f32x4;

// x ~= hi + lo, both bf16 (RNE). hi*whi + hi*wlo + lo*whi gives ~2^-16 rel err.
__device__ __forceinline__ void bf16_split(float x, ushort& hi, ushort& lo) {
  unsigned u = __float_as_uint(x);
  ushort h = (ushort)((u + 0x7FFFu + ((u >> 16) & 1u)) >> 16);
  float r = x - __uint_as_float(((unsigned)h) << 16);  // exact in fp32
  unsigned v = __float_as_uint(r);
  ushort l = (ushort)((v + 0x7FFFu + ((v >> 16) & 1u)) >> 16);
  hi = h;
  lo = l;
}

__device__ __forceinline__ void split8(const float4 v0, const float4 v1,
                                       short8& hi, short8& lo) {
  float x[8] = {v0.x, v0.y, v0.z, v0.w, v1.x, v1.y, v1.z, v1.w};
#pragma unroll
  for (int j = 0; j < 8; ++j) {
    ushort h, l;
    bf16_split(x[j], h, l);
    hi[j] = (short)h;
    lo[j] = (short)l;
  }
}

// ---------------- bin1: coarse-bucket scatter, LDS line-coalesced flush -------
// Entry: (dst & 1023) << 17 | src  (src < 2^17). Bucket = dst >> 10.
// Bucket c's region: ebuf[c*CAPB ...); gcur[c] (zero-init) is both append
// cursor and final entry count. All ebuf writes are contiguous 128B runs.
__global__ __launch_bounds__(256) void bin1_kernel(const int* __restrict__ src,
                                                   const int* __restrict__ dst,
                                                   int* __restrict__ gcur,
                                                   unsigned* __restrict__ ebuf) {
  __shared__ unsigned stage[NBUCK][CAP];
  __shared__ int scnt[NBUCK];
  const int t = threadIdx.x;
  for (int i = t; i < NBUCK; i += 256) scnt[i] = 0;
  __syncthreads();
  const int e0 = blockIdx.x * BIN1_EPW;
  for (int r = 0; r < BIN1_EPW / 1024; ++r) {
    unsigned item[4];
    int buck[4];
    int pend[4];
#pragma unroll
    for (int j = 0; j < 4; ++j) {
      pend[j] = 0;
      int e = e0 + r * 1024 + j * 256 + t;
      if (e < NEDGES) {
        int d = dst[e];
        int s = src[e];
        buck[j] = d >> 10;
        item[j] = ((unsigned)(d & 1023) << 17) | (unsigned)s;
        int p = atomicAdd(&scnt[buck[j]], 1);
        if (p < CAP)
          stage[buck[j]][p] = item[j];
        else
          pend[j] = 1;
      }
    }
    int pendLeft;
    do {
      __syncthreads();  // stage writes visible to flushers
      if (t < NBUCK && scnt[t] >= CAP) {
        int base = t * CAPB + atomicAdd(&gcur[t], CAP);
        for (int q = 0; q < CAP; ++q) ebuf[base + q] = stage[t][q];
        scnt[t] = 0;  // phantom counts beyond CAP re-insert below
      }
      __syncthreads();  // resets visible before retry
      int mypend = 0;
#pragma unroll
      for (int j = 0; j < 4; ++j) {
        if (pend[j]) {
          int p = atomicAdd(&scnt[buck[j]], 1);
          if (p < CAP) {
            stage[buck[j]][p] = item[j];
            pend[j] = 0;
          } else {
            mypend = 1;
          }
        }
      }
      pendLeft = __syncthreads_count(mypend);
    } while (pendLeft > 0);
  }
  // final flush (scnt may be exactly CAP; all entries valid)
  __syncthreads();
  if (t < NBUCK) {
    int n = scnt[t];
    if (n > 0) {
      int base = t * CAPB + atomicAdd(&gcur[t], n);
      for (int q = 0; q < n; ++q) ebuf[base + q] = stage[t][q];
    }
  }
}

// ---------------- bscan: exclusive scan of 98 bucket counts -> bbase ---------
__global__ __launch_bounds__(128) void bscan_kernel(const int* __restrict__ gcur,
                                                    int* __restrict__ bbase,
                                                    int* __restrict__ offs) {
  __shared__ int s[128];
  const int t = threadIdx.x;
  int v = (t < NBUCK) ? gcur[t] : 0;
  s[t] = v;
  __syncthreads();
  for (int off = 1; off < 128; off <<= 1) {
    int u = (t >= off) ? s[t - off] : 0;
    __syncthreads();
    s[t] += u;
    __syncthreads();
  }
  if (t < NBUCK) bbase[t] = s[t] - v;
  if (t == NBUCK - 1) offs[NNODES] = s[t];
}

// ---------------- bucket_csr: LDS hist + scan + scatter, one bucket/block ----
// Replaces hist/bsum/offs/bin2: per-node counts and exact CSR positions are
// derived from the bucket's own (L2-hot) entries.
__global__ __launch_bounds__(1024) void bucket_csr_kernel(const unsigned* __restrict__ ebuf,
                                                          const int* __restrict__ gcur,
                                                          const int* __restrict__ bbase,
                                                          int* __restrict__ offs,
                                                          int* __restrict__ esrc) {
  __shared__ int h[1024];
  __shared__ int cur[1024];
  const int t = threadIdx.x;
  const int c = blockIdx.x;
  const int n = gcur[c];
  const unsigned* eb = ebuf + c * CAPB;
  h[t] = 0;
  __syncthreads();
  for (int i = t; i < n; i += 1024) atomicAdd(&h[eb[i] >> 17], 1);
  __syncthreads();
  int v = h[t];
  for (int off = 1; off < 1024; off <<= 1) {
    int u = (t >= off) ? h[t - off] : 0;
    __syncthreads();
    h[t] += u;
    __syncthreads();
  }
  int excl = h[t] - v + bbase[c];
  int node = (c << 10) + t;
  if (node < NNODES) offs[node] = excl;
  cur[t] = excl;
  __syncthreads();
  for (int i = t; i < n; i += 1024) {
    unsigned e = eb[i];
    int p = atomicAdd(&cur[e >> 17], 1);
    esrc[p] = (int)(e & 0x1FFFFu);
  }
}

// ---------------- gather-aggregate: 4-way unrolled edge loop -----------------
__global__ __launch_bounds__(256) void agg_kernel(const float* __restrict__ nf,
                                                  const int* __restrict__ offs,
                                                  const int* __restrict__ esrc,
                                                  float* __restrict__ agg) {
  const int t = threadIdx.x;
  const int node = blockIdx.x * 8 + (t >> 5);
  const int c4 = (t & 31) << 2;
  const int beg = offs[node];
  const int end = offs[node + 1];
  float4 a0 = make_float4(0.f, 0.f, 0.f, 0.f);
  float4 a1 = make_float4(0.f, 0.f, 0.f, 0.f);
  float4 a2 = make_float4(0.f, 0.f, 0.f, 0.f);
  float4 a3 = make_float4(0.f, 0.f, 0.f, 0.f);
  int i = beg;
  for (; i + 3 < end; i += 4) {
    int s0 = esrc[i];
    int s1 = esrc[i + 1];
    int s2 = esrc[i + 2];
    int s3 = esrc[i + 3];
    float4 v0 = *(const float4*)&nf[s0 * DD + c4];
    float4 v1 = *(const float4*)&nf[s1 * DD + c4];
    float4 v2 = *(const float4*)&nf[s2 * DD + c4];
    float4 v3 = *(const float4*)&nf[s3 * DD + c4];
    a0.x += v0.x; a0.y += v0.y; a0.z += v0.z; a0.w += v0.w;
    a1.x += v1.x; a1.y += v1.y; a1.z += v1.z; a1.w += v1.w;
    a2.x += v2.x; a2.y += v2.y; a2.z += v2.z; a2.w += v2.w;
    a3.x += v3.x; a3.y += v3.y; a3.z += v3.z; a3.w += v3.w;
  }
  for (; i < end; ++i) {
    int s0 = esrc[i];
    float4 v0 = *(const float4*)&nf[s0 * DD + c4];
    a0.x += v0.x; a0.y += v0.y; a0.z += v0.z; a0.w += v0.w;
  }
  a0.x += a1.x; a0.y += a1.y; a0.z += a1.z; a0.w += a1.w;
  a2.x += a3.x; a2.y += a3.y; a2.z += a3.z; a2.w += a3.w;
  a0.x += a2.x; a0.y += a2.y; a0.z += a2.z; a0.w += a2.w;
  *(float4*)&agg[node * DD + c4] = a0;
}

// ---------------- weight prep: fp32 -> split-bf16, tile-packed ----------------
__global__ __launch_bounds__(256) void wprep_kernel(const float* __restrict__ W1,
                                                    const float* __restrict__ W2,
                                                    const float* __restrict__ W3,
                                                    ushort* __restrict__ wt) {
  int tid = blockIdx.x * 256 + threadIdx.x;  // 65536 total
  const float* W;
  int dstHi, dstLo, k, col;
  if (tid < 32768) {  // layer 1, K=256: tiles = c16*8 + kk
    int j = tid & 7, l = (tid >> 3) & 63, tile = tid >> 9;
    int kk = tile & 7, c16 = tile >> 3;
    k = kk * 32 + (l >> 4) * 8 + j;
    col = c16 * 16 + (l & 15);
    W = W1;
    dstHi = WT1HI + tid;
    dstLo = WT1LO + tid;
  } else {  // layers 2/3, K=128: tiles = c16*4 + kk
    int t2 = tid - 32768;
    int which = t2 >> 14;
    int t1 = t2 & 16383;
    int j = t1 & 7, l = (t1 >> 3) & 63, tile = t1 >> 9;
    int kk = tile & 3, c16 = tile >> 2;
    k = kk * 32 + (l >> 4) * 8 + j;
    col = c16 * 16 + (l & 15);
    W = which ? W3 : W2;
    dstHi = (which ? WT3HI : WT2HI) + t1;
    dstLo = (which ? WT3LO : WT2LO) + t1;
  }
  ushort hi, lo;
  bf16_split(W[k * DD + col], hi, lo);
  wt[dstHi] = hi;
  wt[dstLo] = lo;
}

// ---------------- MFMA MLP (unchanged from R3) ----------------
__device__ __forceinline__ void store_h(ushort* Hh, ushort* Hl,
                                        const float* __restrict__ b,
                                        int wr, int wc, int l15, int lhi,
                                        f32x4 acc[2][4]) {
#pragma unroll
  for (int rt = 0; rt < 2; ++rt) {
#pragma unroll
    for (int ct = 0; ct < 4; ++ct) {
      int col = wc * 64 + ct * 16 + l15;
      float bias = b[col];
#pragma unroll
      for (int i = 0; i < 4; ++i) {
        int row = wr * 32 + rt * 16 + lhi * 4 + i;
        float v = fmaxf(acc[rt][ct][i] + bias, 0.f);
        ushort h, l;
        bf16_split(v, h, l);
        int byte = (row * 256 + col * 2) ^ ((row & 7) << 4);
        *(ushort*)((char*)Hh + byte) = h;
        *(ushort*)((char*)Hl + byte) = l;
      }
    }
  }
}

__device__ __forceinline__ void l1_step(const float* __restrict__ srcb,
                                        const ushort* __restrict__ wt,
                                        int kkTile, int kOff, const int rowA[2],
                                        int wc, int lane, int lhi,
                                        f32x4 acc[2][4]) {
  short8 ahi[2], alo[2];
#pragma unroll
  for (int rt = 0; rt < 2; ++rt) {
    const float* p = srcb + rowA[rt] * DD + kOff + lhi * 8;
    float4 v0 = *(const float4*)p;
    float4 v1 = *(const float4*)(p + 4);
    split8(v0, v1, ahi[rt], alo[rt]);
  }
#pragma unroll
  for (int ct = 0; ct < 4; ++ct) {
    int tb = ((wc * 4 + ct) * 8 + kkTile) * 512 + lane * 8;
    short8 bhi = *(const short8*)&wt[WT1HI + tb];
    short8 blo = *(const short8*)&wt[WT1LO + tb];
#pragma unroll
    for (int rt = 0; rt < 2; ++rt) {
      acc[rt][ct] = __builtin_amdgcn_mfma_f32_16x16x32_bf16(ahi[rt], bhi, acc[rt][ct], 0, 0, 0);
      acc[rt][ct] = __builtin_amdgcn_mfma_f32_16x16x32_bf16(ahi[rt], blo, acc[rt][ct], 0, 0, 0);
      acc[rt][ct] = __builtin_amdgcn_mfma_f32_16x16x32_bf16(alo[rt], bhi, acc[rt][ct], 0, 0, 0);
    }
  }
}

__device__ __forceinline__ void layer_lds(const ushort* Hh, const ushort* Hl,
                                          const ushort* __restrict__ WhiT,
                                          const ushort* __restrict__ WloT,
                                          int wr, int wc, int lane, int l15,
                                          int lhi, f32x4 acc[2][4]) {
#pragma unroll 2
  for (int kk = 0; kk < 4; ++kk) {
    short8 ahi[2], alo[2];
#pragma unroll
    for (int rt = 0; rt < 2; ++rt) {
      int row = wr * 32 + rt * 16 + l15;
      int byte = (row * 256 + kk * 64 + lhi * 16) ^ ((row & 7) << 4);
      ahi[rt] = *(const short8*)((const char*)Hh + byte);
      alo[rt] = *(const short8*)((const char*)Hl + byte);
    }
#pragma unroll
    for (int ct = 0; ct < 4; ++ct) {
      int tb = ((wc * 4 + ct) * 4 + kk) * 512 + lane * 8;
      short8 bhi = *(const short8*)&WhiT[tb];
      short8 blo = *(const short8*)&WloT[tb];
#pragma unroll
      for (int rt = 0; rt < 2; ++rt) {
        acc[rt][ct] = __builtin_amdgcn_mfma_f32_16x16x32_bf16(ahi[rt], bhi, acc[rt][ct], 0, 0, 0);
        acc[rt][ct] = __builtin_amdgcn_mfma_f32_16x16x32_bf16(ahi[rt], blo, acc[rt][ct], 0, 0, 0);
        acc[rt][ct] = __builtin_amdgcn_mfma_f32_16x16x32_bf16(alo[rt], bhi, acc[rt][ct], 0, 0, 0);
      }
    }
  }
}

__global__ __launch_bounds__(256, 4) void mlp_kernel(const float* __restrict__ agg,
                                                     const float* __restrict__ nf,
                                                     const ushort* __restrict__ wt,
                                                     const float* __restrict__ b1,
                                                     const float* __restrict__ b2,
                                                     const float* __restrict__ b3,
                                                     float* __restrict__ out) {
  __shared__ ushort smem[16384];
  ushort* Hhi = smem;
  ushort* Hlo = smem + 8192;

  const int t = threadIdx.x;
  const int lane = t & 63;
  const int w = t >> 6;
  const int wr = w & 1;
  const int wc = w >> 1;
  const int l15 = lane & 15;
  const int lhi = lane >> 4;
  const int base = blockIdx.x * BM;

  int rowA[2];
  {
    int r0 = base + wr * 32 + l15;
    rowA[0] = min(r0, NNODES - 1);
    rowA[1] = min(r0 + 16, NNODES - 1);
  }

  const f32x4 z = {0.f, 0.f, 0.f, 0.f};
  f32x4 acc[2][4];

#pragma unroll
  for (int rt = 0; rt < 2; ++rt)
#pragma unroll
    for (int ct = 0; ct < 4; ++ct) acc[rt][ct] = z;
#pragma unroll 2
  for (int kk = 0; kk < 4; ++kk)
    l1_step(agg, wt, kk, kk * 32, rowA, wc, lane, lhi, acc);
#pragma unroll 2
  for (int kk = 0; kk < 4; ++kk)
    l1_step(nf, wt, kk + 4, kk * 32, rowA, wc, lane, lhi, acc);
  store_h(Hhi, Hlo, b1, wr, wc, l15, lhi, acc);
  __syncthreads();

#pragma unroll
  for (int rt = 0; rt < 2; ++rt)
#pragma unroll
    for (int ct = 0; ct < 4; ++ct) acc[rt][ct] = z;
  layer_lds(Hhi, Hlo, wt + WT2HI, wt + WT2LO, wr, wc, lane, l15, lhi, acc);
  __syncthreads();
  store_h(Hhi, Hlo, b2, wr, wc, l15, lhi, acc);
  __syncthreads();

#pragma unroll
  for (int rt = 0; rt < 2; ++rt)
#pragma unroll
    for (int ct = 0; ct < 4; ++ct) acc[rt][ct] = z;
  layer_lds(Hhi, Hlo, wt + WT3HI, wt + WT3LO, wr, wc, lane, l15, lhi, acc);
#pragma unroll
  for (int rt = 0; rt < 2; ++rt) {
#pragma unroll
    for (int ct = 0; ct < 4; ++ct) {
      int col = wc * 64 + ct * 16 + l15;
      float bias = b3[col];
#pragma unroll
      for (int i = 0; i < 4; ++i) {
        int row = base + wr * 32 + rt * 16 + lhi * 4 + i;
        if (row < NNODES) out[row * DD + col] = acc[rt][ct][i] + bias;
      }
    }
  }
}

extern "C" void kernel_launch(void* const* d_in, const int* in_sizes, int n_in,
                              void* d_out, int out_size, void* d_ws, size_t ws_size,
                              hipStream_t stream) {
  const float* nf = (const float*)d_in[0];
  const int* src = (const int*)d_in[1];
  const int* dst = (const int*)d_in[2];
  const float* W1 = (const float*)d_in[3];
  const float* b1 = (const float*)d_in[4];
  const float* W2 = (const float*)d_in[5];
  const float* b2 = (const float*)d_in[6];
  const float* W3 = (const float*)d_in[7];
  const float* b3 = (const float*)d_in[8];
  float* out = (float*)d_out;

  int* wsi = (int*)d_ws;
  int* gcur = wsi + WS_GCUR;    // 98: bucket cursors / counts
  int* bbase = wsi + WS_BBASE;  // 98: exclusive bucket bases
  int* offs = wsi + WS_OFFS;    // 100001
  int* esrc = wsi + WS_ESRC;    // 1600000
  ushort* wt = (ushort*)wsi;    // 256KB weight tables in [0,100000) region

  // Scratch carved from `out`: fixed-capacity coarse-bucket edge buffer
  // (98 x 20480 x 4B = 8.0MB). Dead after bucket_csr; agg rewrites all of out.
  unsigned* ebuf = (unsigned*)out;
  float* agg = out;  // agg aliases d_out (same discipline as before)

  hipMemsetAsync(gcur, 0, NBUCK * sizeof(int), stream);
  bin1_kernel<<<BIN1_WGS, 256, 0, stream>>>(src, dst, gcur, ebuf);
  bscan_kernel<<<1, 128, 0, stream>>>(gcur, bbase, offs);
  bucket_csr_kernel<<<NBUCK, 1024, 0, stream>>>(ebuf, gcur, bbase, offs, esrc);
  wprep_kernel<<<256, 256, 0, stream>>>(W1, W2, W3, wt);
  agg_kernel<<<NNODES / 8, 256, 0, stream>>>(nf, offs, esrc, agg);
  mlp_kernel<<<NBLK_MLP, 256, 0, stream>>>(agg, nf, wt, b1, b2, b3, out);
}

// Round 6
// 240.287 us; speedup vs baseline: 3.1051x; 1.0566x over previous
//
#include <hip/hip_runtime.h>

#define NNODES 100000
#define NEDGES 1600000
#define DD 128
#define BM 64
#define NBUCK 98                           // coarse buckets of 1024 nodes
#define NBLK_MLP ((NNODES + BM - 1) / BM)  // 1563
#define CAP 32                             // bin1 LDS staging entries per bucket
#define CAPB 20480                         // ebuf capacity per bucket (mean 16327)
#define BIN1_WGS 200
#define BIN1_EPW 8192                      // edges per workgroup (8 rounds x 1024)

// ---------------- workspace layout (ints) ----------------
// [0,100000): weight tables (ushort view)
// [100000,100098): gcur | [100128,100226): bbase
// [100352,200353): offs | [201216,1801216): esrc
#define WS_GCUR 100000
#define WS_BBASE 100128
#define WS_OFFS 100352
#define WS_ESRC 201216

// ushort offsets inside the weight-table region (tile-packed)
#define WT1HI 0        // K=256: 8 c16 x 8 kk tiles, 1KB/tile
#define WT1LO 32768
#define WT2HI 65536    // K=128: 8 x 4 tiles
#define WT2LO 81920
#define WT3HI 98304
#define WT3LO 114688

typedef __attribute__((ext_vector_type(8))) short short8;  // 8 bf16
typedef __attribute__((ext_vector_type(4))) float f32x4;

// x ~= hi + lo, both bf16 (RNE). hi*whi + hi*wlo + lo*whi gives ~2^-16 rel err.
__device__ __forceinline__ void bf16_split(float x, ushort& hi, ushort& lo) {
  unsigned u = __float_as_uint(x);
  ushort h = (ushort)((u + 0x7FFFu + ((u >> 16) & 1u)) >> 16);
  float r = x - __uint_as_float(((unsigned)h) << 16);  // exact in fp32
  unsigned v = __float_as_uint(r);
  ushort l = (ushort)((v + 0x7FFFu + ((v >> 16) & 1u)) >> 16);
  hi = h;
  lo = l;
}

__device__ __forceinline__ void split8(const float4 v0, const float4 v1,
                                       short8& hi, short8& lo) {
  float x[8] = {v0.x, v0.y, v0.z, v0.w, v1.x, v1.y, v1.z, v1.w};
#pragma unroll
  for (int j = 0; j < 8; ++j) {
    ushort h, l;
    bf16_split(x[j], h, l);
    hi[j] = (short)h;
    lo[j] = (short)l;
  }
}

// ---------------- bin1: coarse-bucket scatter, LDS line-coalesced flush -------
__global__ __launch_bounds__(256) void bin1_kernel(const int* __restrict__ src,
                                                   const int* __restrict__ dst,
                                                   int* __restrict__ gcur,
                                                   unsigned* __restrict__ ebuf) {
  __shared__ unsigned stage[NBUCK][CAP];
  __shared__ int scnt[NBUCK];
  const int t = threadIdx.x;
  for (int i = t; i < NBUCK; i += 256) scnt[i] = 0;
  __syncthreads();
  const int e0 = blockIdx.x * BIN1_EPW;
  for (int r = 0; r < BIN1_EPW / 1024; ++r) {
    unsigned item[4];
    int buck[4];
    int pend[4];
#pragma unroll
    for (int j = 0; j < 4; ++j) {
      pend[j] = 0;
      int e = e0 + r * 1024 + j * 256 + t;
      if (e < NEDGES) {
        int d = dst[e];
        int s = src[e];
        buck[j] = d >> 10;
        item[j] = ((unsigned)(d & 1023) << 17) | (unsigned)s;
        int p = atomicAdd(&scnt[buck[j]], 1);
        if (p < CAP)
          stage[buck[j]][p] = item[j];
        else
          pend[j] = 1;
      }
    }
    int pendLeft;
    do {
      __syncthreads();
      if (t < NBUCK && scnt[t] >= CAP) {
        int base = t * CAPB + atomicAdd(&gcur[t], CAP);
        for (int q = 0; q < CAP; ++q) ebuf[base + q] = stage[t][q];
        scnt[t] = 0;
      }
      __syncthreads();
      int mypend = 0;
#pragma unroll
      for (int j = 0; j < 4; ++j) {
        if (pend[j]) {
          int p = atomicAdd(&scnt[buck[j]], 1);
          if (p < CAP) {
            stage[buck[j]][p] = item[j];
            pend[j] = 0;
          } else {
            mypend = 1;
          }
        }
      }
      pendLeft = __syncthreads_count(mypend);
    } while (pendLeft > 0);
  }
  __syncthreads();
  if (t < NBUCK) {
    int n = scnt[t];
    if (n > 0) {
      int base = t * CAPB + atomicAdd(&gcur[t], n);
      for (int q = 0; q < n; ++q) ebuf[base + q] = stage[t][q];
    }
  }
}

// ---------------- bscan: exclusive scan of 98 bucket counts ------------------
__global__ __launch_bounds__(128) void bscan_kernel(const int* __restrict__ gcur,
                                                    int* __restrict__ bbase,
                                                    int* __restrict__ offs) {
  __shared__ int s[128];
  const int t = threadIdx.x;
  int v = (t < NBUCK) ? gcur[t] : 0;
  s[t] = v;
  __syncthreads();
  for (int off = 1; off < 128; off <<= 1) {
    int u = (t >= off) ? s[t - off] : 0;
    __syncthreads();
    s[t] += u;
    __syncthreads();
  }
  if (t < NBUCK) bbase[t] = s[t] - v;
  if (t == NBUCK - 1) offs[NNODES] = s[t];
}

// ---------------- bucket_csr: LDS hist + scan + scatter ----------------------
__global__ __launch_bounds__(1024) void bucket_csr_kernel(const unsigned* __restrict__ ebuf,
                                                          const int* __restrict__ gcur,
                                                          const int* __restrict__ bbase,
                                                          int* __restrict__ offs,
                                                          int* __restrict__ esrc) {
  __shared__ int h[1024];
  __shared__ int cur[1024];
  const int t = threadIdx.x;
  const int c = blockIdx.x;
  const int n = gcur[c];
  const unsigned* eb = ebuf + c * CAPB;
  h[t] = 0;
  __syncthreads();
  for (int i = t; i < n; i += 1024) atomicAdd(&h[eb[i] >> 17], 1);
  __syncthreads();
  int v = h[t];
  for (int off = 1; off < 1024; off <<= 1) {
    int u = (t >= off) ? h[t - off] : 0;
    __syncthreads();
    h[t] += u;
    __syncthreads();
  }
  int excl = h[t] - v + bbase[c];
  int node = (c << 10) + t;
  if (node < NNODES) offs[node] = excl;
  cur[t] = excl;
  __syncthreads();
  for (int i = t; i < n; i += 1024) {
    unsigned e = eb[i];
    int p = atomicAdd(&cur[e >> 17], 1);
    esrc[p] = (int)(e & 0x1FFFFu);
  }
}

// ---------------- weight prep: fp32 -> split-bf16, tile-packed ----------------
__global__ __launch_bounds__(256) void wprep_kernel(const float* __restrict__ W1,
                                                    const float* __restrict__ W2,
                                                    const float* __restrict__ W3,
                                                    ushort* __restrict__ wt) {
  int tid = blockIdx.x * 256 + threadIdx.x;  // 65536 total
  const float* W;
  int dstHi, dstLo, k, col;
  if (tid < 32768) {  // layer 1, K=256: tiles = c16*8 + kk
    int j = tid & 7, l = (tid >> 3) & 63, tile = tid >> 9;
    int kk = tile & 7, c16 = tile >> 3;
    k = kk * 32 + (l >> 4) * 8 + j;
    col = c16 * 16 + (l & 15);
    W = W1;
    dstHi = WT1HI + tid;
    dstLo = WT1LO + tid;
  } else {  // layers 2/3, K=128: tiles = c16*4 + kk
    int t2 = tid - 32768;
    int which = t2 >> 14;
    int t1 = t2 & 16383;
    int j = t1 & 7, l = (t1 >> 3) & 63, tile = t1 >> 9;
    int kk = tile & 3, c16 = tile >> 2;
    k = kk * 32 + (l >> 4) * 8 + j;
    col = c16 * 16 + (l & 15);
    W = which ? W3 : W2;
    dstHi = (which ? WT3HI : WT2HI) + t1;
    dstLo = (which ? WT3LO : WT2LO) + t1;
  }
  ushort hi, lo;
  bf16_split(W[k * DD + col], hi, lo);
  wt[dstHi] = hi;
  wt[dstLo] = lo;
}

// ---------------- fused gather + MFMA MLP ----------------
// Frag maps (verified): A: lane l = A[row=l&15][k=(l>>4)*8+j];
// B: lane l = B[k=(l>>4)*8+j][col=l&15]; D: lane l reg i = [(l>>4)*4+i][l&15].

// kk local k-steps from swizzled LDS ([64][128] ushort, 256B row stride);
// KT = k-tile count of the weight table, tileOff = starting tile.
template <int KT>
__device__ __forceinline__ void lds_ksteps(const ushort* Hh, const ushort* Hl,
                                           const ushort* __restrict__ WhiT,
                                           const ushort* __restrict__ WloT,
                                           int tileOff, int wr, int wc, int lane,
                                           int l15, int lhi, f32x4 acc[2][4]) {
#pragma unroll 2
  for (int kk = 0; kk < 4; ++kk) {
    short8 ahi[2], alo[2];
#pragma unroll
    for (int rt = 0; rt < 2; ++rt) {
      int row = wr * 32 + rt * 16 + l15;
      int byte = (row * 256 + kk * 64 + lhi * 16) ^ ((row & 7) << 4);
      ahi[rt] = *(const short8*)((const char*)Hh + byte);
      alo[rt] = *(const short8*)((const char*)Hl + byte);
    }
#pragma unroll
    for (int ct = 0; ct < 4; ++ct) {
      int tb = ((wc * 4 + ct) * KT + tileOff + kk) * 512 + lane * 8;
      short8 bhi = *(const short8*)&WhiT[tb];
      short8 blo = *(const short8*)&WloT[tb];
#pragma unroll
      for (int rt = 0; rt < 2; ++rt) {
        acc[rt][ct] = __builtin_amdgcn_mfma_f32_16x16x32_bf16(ahi[rt], bhi, acc[rt][ct], 0, 0, 0);
        acc[rt][ct] = __builtin_amdgcn_mfma_f32_16x16x32_bf16(ahi[rt], blo, acc[rt][ct], 0, 0, 0);
        acc[rt][ct] = __builtin_amdgcn_mfma_f32_16x16x32_bf16(alo[rt], bhi, acc[rt][ct], 0, 0, 0);
      }
    }
  }
}

// one 32-k step with A from global memory (nf half of layer 1)
__device__ __forceinline__ void l1_step(const float* __restrict__ srcb,
                                        const ushort* __restrict__ wt,
                                        int kkTile, int kOff, const int rowA[2],
                                        int wc, int lane, int lhi,
                                        f32x4 acc[2][4]) {
  short8 ahi[2], alo[2];
#pragma unroll
  for (int rt = 0; rt < 2; ++rt) {
    const float* p = srcb + rowA[rt] * DD + kOff + lhi * 8;
    float4 v0 = *(const float4*)p;
    float4 v1 = *(const float4*)(p + 4);
    split8(v0, v1, ahi[rt], alo[rt]);
  }
#pragma unroll
  for (int ct = 0; ct < 4; ++ct) {
    int tb = ((wc * 4 + ct) * 8 + kkTile) * 512 + lane * 8;
    short8 bhi = *(const short8*)&wt[WT1HI + tb];
    short8 blo = *(const short8*)&wt[WT1LO + tb];
#pragma unroll
    for (int rt = 0; rt < 2; ++rt) {
      acc[rt][ct] = __builtin_amdgcn_mfma_f32_16x16x32_bf16(ahi[rt], bhi, acc[rt][ct], 0, 0, 0);
      acc[rt][ct] = __builtin_amdgcn_mfma_f32_16x16x32_bf16(ahi[rt], blo, acc[rt][ct], 0, 0, 0);
      acc[rt][ct] = __builtin_amdgcn_mfma_f32_16x16x32_bf16(alo[rt], bhi, acc[rt][ct], 0, 0, 0);
    }
  }
}

// bias + ReLU + split-bf16 + swizzled LDS store
__device__ __forceinline__ void store_h(ushort* Hh, ushort* Hl,
                                        const float* __restrict__ b,
                                        int wr, int wc, int l15, int lhi,
                                        f32x4 acc[2][4]) {
#pragma unroll
  for (int rt = 0; rt < 2; ++rt) {
#pragma unroll
    for (int ct = 0; ct < 4; ++ct) {
      int col = wc * 64 + ct * 16 + l15;
      float bias = b[col];
#pragma unroll
      for (int i = 0; i < 4; ++i) {
        int row = wr * 32 + rt * 16 + lhi * 4 + i;
        float v = fmaxf(acc[rt][ct][i] + bias, 0.f);
        ushort h, l;
        bf16_split(v, h, l);
        int byte = (row * 256 + col * 2) ^ ((row & 7) << 4);
        *(ushort*)((char*)Hh + byte) = h;
        *(ushort*)((char*)Hl + byte) = l;
      }
    }
  }
}

__global__ __launch_bounds__(256, 4) void fused_kernel(const float* __restrict__ nf,
                                                       const int* __restrict__ offs,
                                                       const int* __restrict__ esrc,
                                                       const ushort* __restrict__ wt,
                                                       const float* __restrict__ b1,
                                                       const float* __restrict__ b2,
                                                       const float* __restrict__ b3,
                                                       float* __restrict__ out) {
  // X (agg, split-bf16, swizzled) [64][128] hi/lo = 32KB.
  // H1 and H2 reuse the same region (barrier-separated).
  __shared__ ushort smem[16384];
  ushort* Xhi = smem;
  ushort* Xlo = smem + 8192;

  const int t = threadIdx.x;
  const int lane = t & 63;
  const int w = t >> 6;
  const int wr = w & 1;
  const int wc = w >> 1;
  const int l15 = lane & 15;
  const int lhi = lane >> 4;
  const int base = blockIdx.x * BM;

  // ---- phase 1: gather-aggregate this block's 64 nodes into X ----
  {
    const int g = t >> 5;        // 8 groups of 32 lanes
    const int l32 = t & 31;
    const int col = l32 << 2;    // 4 floats per lane
    for (int j = 0; j < 8; ++j) {
      const int r = g * 8 + j;   // block-local row
      const int node = base + r;
      float4 a0 = make_float4(0.f, 0.f, 0.f, 0.f);
      float4 a1 = make_float4(0.f, 0.f, 0.f, 0.f);
      float4 a2 = make_float4(0.f, 0.f, 0.f, 0.f);
      float4 a3 = make_float4(0.f, 0.f, 0.f, 0.f);
      if (node < NNODES) {
        const int beg = offs[node];
        const int end = offs[node + 1];
        int i = beg;
        for (; i + 3 < end; i += 4) {
          int s0 = esrc[i];
          int s1 = esrc[i + 1];
          int s2 = esrc[i + 2];
          int s3 = esrc[i + 3];
          float4 v0 = *(const float4*)&nf[s0 * DD + col];
          float4 v1 = *(const float4*)&nf[s1 * DD + col];
          float4 v2 = *(const float4*)&nf[s2 * DD + col];
          float4 v3 = *(const float4*)&nf[s3 * DD + col];
          a0.x += v0.x; a0.y += v0.y; a0.z += v0.z; a0.w += v0.w;
          a1.x += v1.x; a1.y += v1.y; a1.z += v1.z; a1.w += v1.w;
          a2.x += v2.x; a2.y += v2.y; a2.z += v2.z; a2.w += v2.w;
          a3.x += v3.x; a3.y += v3.y; a3.z += v3.z; a3.w += v3.w;
        }
        for (; i < end; ++i) {
          int s0 = esrc[i];
          float4 v0 = *(const float4*)&nf[s0 * DD + col];
          a0.x += v0.x; a0.y += v0.y; a0.z += v0.z; a0.w += v0.w;
        }
      }
      a0.x += a1.x; a0.y += a1.y; a0.z += a1.z; a0.w += a1.w;
      a2.x += a3.x; a2.y += a3.y; a2.z += a3.z; a2.w += a3.w;
      a0.x += a2.x; a0.y += a2.y; a0.z += a2.z; a0.w += a2.w;
      ushort h0, h1, h2, h3, l0, l1, l2, l3;
      bf16_split(a0.x, h0, l0);
      bf16_split(a0.y, h1, l1);
      bf16_split(a0.z, h2, l2);
      bf16_split(a0.w, h3, l3);
      int byte = (r * 256 + col * 2) ^ ((r & 7) << 4);
      *(ushort4*)((char*)Xhi + byte) = make_ushort4(h0, h1, h2, h3);
      *(ushort4*)((char*)Xlo + byte) = make_ushort4(l0, l1, l2, l3);
    }
  }
  __syncthreads();

  // nf rows for the global half of layer 1 (clamped; stores are guarded)
  int rowA[2];
  {
    int r0 = base + wr * 32 + l15;
    rowA[0] = min(r0, NNODES - 1);
    rowA[1] = min(r0 + 16, NNODES - 1);
  }

  const f32x4 z = {0.f, 0.f, 0.f, 0.f};
  f32x4 acc[2][4];

  // ---- layer 1: k 0..127 from X (LDS), k 128..255 from nf (global) ----
#pragma unroll
  for (int rt = 0; rt < 2; ++rt)
#pragma unroll
    for (int ct = 0; ct < 4; ++ct) acc[rt][ct] = z;
  lds_ksteps<8>(Xhi, Xlo, wt + WT1HI, wt + WT1LO, 0, wr, wc, lane, l15, lhi, acc);
#pragma unroll 2
  for (int kk = 0; kk < 4; ++kk)
    l1_step(nf, wt, kk + 4, kk * 32, rowA, wc, lane, lhi, acc);
  __syncthreads();  // all reads of X done before H1 overwrites it
  store_h(Xhi, Xlo, b1, wr, wc, l15, lhi, acc);
  __syncthreads();

  // ---- layer 2 ----
#pragma unroll
  for (int rt = 0; rt < 2; ++rt)
#pragma unroll
    for (int ct = 0; ct < 4; ++ct) acc[rt][ct] = z;
  lds_ksteps<4>(Xhi, Xlo, wt + WT2HI, wt + WT2LO, 0, wr, wc, lane, l15, lhi, acc);
  __syncthreads();
  store_h(Xhi, Xlo, b2, wr, wc, l15, lhi, acc);
  __syncthreads();

  // ---- layer 3 ----
#pragma unroll
  for (int rt = 0; rt < 2; ++rt)
#pragma unroll
    for (int ct = 0; ct < 4; ++ct) acc[rt][ct] = z;
  lds_ksteps<4>(Xhi, Xlo, wt + WT3HI, wt + WT3LO, 0, wr, wc, lane, l15, lhi, acc);
#pragma unroll
  for (int rt = 0; rt < 2; ++rt) {
#pragma unroll
    for (int ct = 0; ct < 4; ++ct) {
      int col = wc * 64 + ct * 16 + l15;
      float bias = b3[col];
#pragma unroll
      for (int i = 0; i < 4; ++i) {
        int row = base + wr * 32 + rt * 16 + lhi * 4 + i;
        if (row < NNODES) out[row * DD + col] = acc[rt][ct][i] + bias;
      }
    }
  }
}

extern "C" void kernel_launch(void* const* d_in, const int* in_sizes, int n_in,
                              void* d_out, int out_size, void* d_ws, size_t ws_size,
                              hipStream_t stream) {
  const float* nf = (const float*)d_in[0];
  const int* src = (const int*)d_in[1];
  const int* dst = (const int*)d_in[2];
  const float* W1 = (const float*)d_in[3];
  const float* b1 = (const float*)d_in[4];
  const float* W2 = (const float*)d_in[5];
  const float* b2 = (const float*)d_in[6];
  const float* W3 = (const float*)d_in[7];
  const float* b3 = (const float*)d_in[8];
  float* out = (float*)d_out;

  int* wsi = (int*)d_ws;
  int* gcur = wsi + WS_GCUR;    // 98: bucket cursors / counts
  int* bbase = wsi + WS_BBASE;  // 98: exclusive bucket bases
  int* offs = wsi + WS_OFFS;    // 100001
  int* esrc = wsi + WS_ESRC;    // 1600000
  ushort* wt = (ushort*)wsi;    // 256KB weight tables in [0,100000) region

  // Scratch carved from `out`: coarse-bucket edge buffer (98 x 20480 x 4B = 8MB).
  // Dead after bucket_csr; fused_kernel later writes every row of out.
  unsigned* ebuf = (unsigned*)out;

  hipMemsetAsync(gcur, 0, NBUCK * sizeof(int), stream);
  bin1_kernel<<<BIN1_WGS, 256, 0, stream>>>(src, dst, gcur, ebuf);
  bscan_kernel<<<1, 128, 0, stream>>>(gcur, bbase, offs);
  bucket_csr_kernel<<<NBUCK, 1024, 0, stream>>>(ebuf, gcur, bbase, offs, esrc);
  wprep_kernel<<<256, 256, 0, stream>>>(W1, W2, W3, wt);
  fused_kernel<<<NBLK_MLP, 256, 0, stream>>>(nf, offs, esrc, wt, b1, b2, b3, out);
}